// Round 1
// baseline (1210.907 us; speedup 1.0000x reference)
//
#include <hip/hip_runtime.h>
#include <cstdint>
#include <cmath>

// Problem constants (fixed by the reference)
constexpr int NB   = 8;      // batch
constexpr int LQn  = 900;    // queries
constexpr int CD   = 256;    // channels
constexpr int NHn  = 8;      // heads
constexpr int DHn  = 32;     // head dim
constexpr int NLn  = 4;      // levels
constexpr int NPn  = 4;      // points
constexpr int DFF  = 1024;
constexpr int LENS = 21760;  // sum of level sizes
constexpr int NQ   = NB * LQn;        // 7200
constexpr int NV   = NB * LENS;       // 174080

// ---------------------------------------------------------------------------
// Elementwise add (float4)
// ---------------------------------------------------------------------------
__global__ void add_kernel(const float* __restrict__ a, const float* __restrict__ b,
                           float* __restrict__ o, int n4) {
    int i = blockIdx.x * blockDim.x + threadIdx.x;
    if (i < n4) {
        float4 va = reinterpret_cast<const float4*>(a)[i];
        float4 vb = reinterpret_cast<const float4*>(b)[i];
        float4 vo;
        vo.x = va.x + vb.x; vo.y = va.y + vb.y; vo.z = va.z + vb.z; vo.w = va.w + vb.w;
        reinterpret_cast<float4*>(o)[i] = vo;
    }
}

// ---------------------------------------------------------------------------
// Tiled fp32 GEMM: C[M x N] = A[M x K] * B[N x K]^T + bias, optional relu,
// optional row-mask zeroing (for padded value rows).
// Tile: BM=128, BN=64, BK=16. Block 256 threads; thread computes 8x4.
// grid = (ceil(M/128), N/64)
// ---------------------------------------------------------------------------
__global__ __launch_bounds__(256) void gemm_nt(
    const float* __restrict__ A, const float* __restrict__ B,
    const float* __restrict__ bias, float* __restrict__ C,
    int M, int K, int ldc, int relu,
    const unsigned char* __restrict__ rowmask)
{
    __shared__ float As[16][128];
    __shared__ float Bs[16][64];

    const int tid = threadIdx.x;
    const int tx = tid & 15;   // output col group (x4)
    const int ty = tid >> 4;   // output row group (x8)
    const size_t bm = (size_t)blockIdx.x * 128;
    const size_t bn = (size_t)blockIdx.y * 64;

    float acc[8][4];
#pragma unroll
    for (int i = 0; i < 8; ++i)
#pragma unroll
        for (int j = 0; j < 4; ++j) acc[i][j] = 0.f;

    // A loader: 512 float4 per tile -> 2 per thread
    const int ar0 = tid >> 2,          ac0 = (tid & 3) * 4;
    const int ar1 = (tid + 256) >> 2,  ac1 = (tid & 3) * 4;
    // B loader: 256 float4 -> 1 per thread
    const int br = tid >> 2, bc = (tid & 3) * 4;

    for (int k0 = 0; k0 < K; k0 += 16) {
        size_t ra0 = bm + ar0; if (ra0 >= (size_t)M) ra0 = M - 1;
        size_t ra1 = bm + ar1; if (ra1 >= (size_t)M) ra1 = M - 1;
        float4 a0 = *reinterpret_cast<const float4*>(A + ra0 * K + k0 + ac0);
        float4 a1 = *reinterpret_cast<const float4*>(A + ra1 * K + k0 + ac1);
        float4 b0 = *reinterpret_cast<const float4*>(B + (bn + br) * (size_t)K + k0 + bc);
        __syncthreads();
        As[ac0 + 0][ar0] = a0.x; As[ac0 + 1][ar0] = a0.y; As[ac0 + 2][ar0] = a0.z; As[ac0 + 3][ar0] = a0.w;
        As[ac1 + 0][ar1] = a1.x; As[ac1 + 1][ar1] = a1.y; As[ac1 + 2][ar1] = a1.z; As[ac1 + 3][ar1] = a1.w;
        Bs[bc + 0][br] = b0.x;  Bs[bc + 1][br] = b0.y;  Bs[bc + 2][br] = b0.z;  Bs[bc + 3][br] = b0.w;
        __syncthreads();
#pragma unroll
        for (int kk = 0; kk < 16; ++kk) {
            float4 av0 = *reinterpret_cast<const float4*>(&As[kk][ty * 8]);
            float4 av1 = *reinterpret_cast<const float4*>(&As[kk][ty * 8 + 4]);
            float4 bv  = *reinterpret_cast<const float4*>(&Bs[kk][tx * 4]);
            float am[8] = {av0.x, av0.y, av0.z, av0.w, av1.x, av1.y, av1.z, av1.w};
            float bb[4] = {bv.x, bv.y, bv.z, bv.w};
#pragma unroll
            for (int i = 0; i < 8; ++i)
#pragma unroll
                for (int j = 0; j < 4; ++j)
                    acc[i][j] = fmaf(am[i], bb[j], acc[i][j]);
        }
    }

    float4 bsv = *reinterpret_cast<const float4*>(bias + bn + tx * 4);
#pragma unroll
    for (int i = 0; i < 8; ++i) {
        size_t r = bm + ty * 8 + i;
        if (r < (size_t)M) {
            float4 o;
            o.x = acc[i][0] + bsv.x; o.y = acc[i][1] + bsv.y;
            o.z = acc[i][2] + bsv.z; o.w = acc[i][3] + bsv.w;
            if (relu) {
                o.x = fmaxf(o.x, 0.f); o.y = fmaxf(o.y, 0.f);
                o.z = fmaxf(o.z, 0.f); o.w = fmaxf(o.w, 0.f);
            }
            if (rowmask && rowmask[r]) { o.x = 0.f; o.y = 0.f; o.z = 0.f; o.w = 0.f; }
            *reinterpret_cast<float4*>(C + r * (size_t)ldc + bn + tx * 4) = o;
        }
    }
}

// ---------------------------------------------------------------------------
// Flash-style self-attention over qkv buffer (NQ x 768: [q|k|v] each 256).
// Block: 256 threads = one (b, h, 64-query tile). Online softmax.
// grid = (ceil(900/64)=15, NH, NB)
// ---------------------------------------------------------------------------
__global__ __launch_bounds__(256) void attn_kernel(
    const float* __restrict__ qkv, float* __restrict__ out)
{
    __shared__ float Qs[32][64];   // [d][q], Q pre-scaled by 1/sqrt(dh)
    __shared__ float Ks[32][64];   // [d][k]
    __shared__ float Vs[64][32];   // [k][d]
    __shared__ float Ps[64][68];   // [k][q] (padded to 16B-aligned rows)

    const int tid = threadIdx.x;
    const int tx = tid & 15;    // key group (x4) / out col pair
    const int ty = tid >> 4;    // query group (x4)
    const int q0 = blockIdx.x * 64;
    const int h  = blockIdx.y;
    const int b  = blockIdx.z;
    const size_t base = (size_t)b * LQn * 768 + h * 32;
    const float sc = 0.17677669529663687f; // 1/sqrt(32)

#pragma unroll
    for (int t = 0; t < 2; ++t) {
        int f = tid + t * 256;
        int row = f >> 3, c4 = (f & 7) * 4;
        int qr = q0 + row; if (qr > LQn - 1) qr = LQn - 1;
        float4 v = *reinterpret_cast<const float4*>(qkv + base + (size_t)qr * 768 + c4);
        Qs[c4 + 0][row] = v.x * sc; Qs[c4 + 1][row] = v.y * sc;
        Qs[c4 + 2][row] = v.z * sc; Qs[c4 + 3][row] = v.w * sc;
    }

    float m[4], l[4], acc[4][2];
#pragma unroll
    for (int i = 0; i < 4; ++i) { m[i] = -INFINITY; l[i] = 0.f; acc[i][0] = 0.f; acc[i][1] = 0.f; }

    for (int kb = 0; kb < LQn; kb += 64) {
        __syncthreads();  // previous iteration's Ps/Ks/Vs reads done
#pragma unroll
        for (int t = 0; t < 2; ++t) {
            int f = tid + t * 256;
            int row = f >> 3, c4 = (f & 7) * 4;
            int kr = kb + row;
            float4 kv, vv;
            if (kr < LQn) {
                kv = *reinterpret_cast<const float4*>(qkv + base + (size_t)kr * 768 + 256 + c4);
                vv = *reinterpret_cast<const float4*>(qkv + base + (size_t)kr * 768 + 512 + c4);
            } else {
                kv = make_float4(0.f, 0.f, 0.f, 0.f); vv = kv;
            }
            Ks[c4 + 0][row] = kv.x; Ks[c4 + 1][row] = kv.y;
            Ks[c4 + 2][row] = kv.z; Ks[c4 + 3][row] = kv.w;
            *reinterpret_cast<float4*>(&Vs[row][c4]) = vv;
        }
        __syncthreads();

        float s[4][4];
#pragma unroll
        for (int i = 0; i < 4; ++i)
#pragma unroll
            for (int j = 0; j < 4; ++j) s[i][j] = 0.f;
#pragma unroll
        for (int d = 0; d < 32; ++d) {
            float4 qa = *reinterpret_cast<const float4*>(&Qs[d][ty * 4]);
            float4 ka = *reinterpret_cast<const float4*>(&Ks[d][tx * 4]);
            float qm[4] = {qa.x, qa.y, qa.z, qa.w};
            float km[4] = {ka.x, ka.y, ka.z, ka.w};
#pragma unroll
            for (int i = 0; i < 4; ++i)
#pragma unroll
                for (int j = 0; j < 4; ++j)
                    s[i][j] = fmaf(qm[i], km[j], s[i][j]);
        }
        if (kb + 64 > LQn) {
#pragma unroll
            for (int j = 0; j < 4; ++j)
                if (kb + tx * 4 + j >= LQn) { s[0][j] = -INFINITY; s[1][j] = -INFINITY; s[2][j] = -INFINITY; s[3][j] = -INFINITY; }
        }

        float pv[4][4];
#pragma unroll
        for (int i = 0; i < 4; ++i) {
            float rm = fmaxf(fmaxf(s[i][0], s[i][1]), fmaxf(s[i][2], s[i][3]));
            rm = fmaxf(rm, __shfl_xor(rm, 1));
            rm = fmaxf(rm, __shfl_xor(rm, 2));
            rm = fmaxf(rm, __shfl_xor(rm, 4));
            rm = fmaxf(rm, __shfl_xor(rm, 8));
            float mn = fmaxf(m[i], rm);
            float esc = __expf(m[i] - mn);
            float rs = 0.f;
#pragma unroll
            for (int j = 0; j < 4; ++j) { pv[i][j] = __expf(s[i][j] - mn); rs += pv[i][j]; }
            rs += __shfl_xor(rs, 1); rs += __shfl_xor(rs, 2);
            rs += __shfl_xor(rs, 4); rs += __shfl_xor(rs, 8);
            l[i] = l[i] * esc + rs;
            m[i] = mn;
            acc[i][0] *= esc; acc[i][1] *= esc;
        }
#pragma unroll
        for (int i = 0; i < 4; ++i)
#pragma unroll
            for (int j = 0; j < 4; ++j)
                Ps[tx * 4 + j][ty * 4 + i] = pv[i][j];
        __syncthreads();
#pragma unroll
        for (int k = 0; k < 64; ++k) {
            float4 p4 = *reinterpret_cast<const float4*>(&Ps[k][ty * 4]);
            float2 v2 = *reinterpret_cast<const float2*>(&Vs[k][tx * 2]);
            float pa[4] = {p4.x, p4.y, p4.z, p4.w};
#pragma unroll
            for (int i = 0; i < 4; ++i) {
                acc[i][0] = fmaf(pa[i], v2.x, acc[i][0]);
                acc[i][1] = fmaf(pa[i], v2.y, acc[i][1]);
            }
        }
    }

#pragma unroll
    for (int i = 0; i < 4; ++i) {
        int qr = q0 + ty * 4 + i;
        if (qr < LQn) {
            float invl = 1.f / l[i];
            float2 o = make_float2(acc[i][0] * invl, acc[i][1] * invl);
            *reinterpret_cast<float2*>(out + ((size_t)b * LQn + qr) * CD + h * 32 + tx * 2) = o;
        }
    }
}

// ---------------------------------------------------------------------------
// Deformable sampling. 32 lanes per (b, q, h); lane = channel d.
// All corner reads are coalesced 128B rows of the value tensor.
// grid = NQ * NH / 8 groups of 32 lanes -> 7200 blocks of 256.
// ---------------------------------------------------------------------------
__global__ __launch_bounds__(256) void deform_kernel(
    const float* __restrict__ value,  // (NB, LENS, 256)
    const float* __restrict__ off,    // (NQ, 256)
    const float* __restrict__ aw,     // (NQ, 128)
    const float* __restrict__ ref,    // (NB, LQ, NL, 2)
    float* __restrict__ out)          // (NQ, 256)
{
    const int grp = (blockIdx.x << 3) + (threadIdx.x >> 5);  // 0..57599
    const int d   = threadIdx.x & 31;
    const int h   = grp & 7;
    const int bq  = grp >> 3;       // 0..7199
    const int b   = bq / LQn;

    // softmax over the 16 attention weights of this (bq, h)
    const float* awp = aw + (size_t)bq * 128 + h * 16;
    float w[16]; float mx = -1e30f;
#pragma unroll
    for (int i = 0; i < 16; ++i) { w[i] = awp[i]; mx = fmaxf(mx, w[i]); }
    float ssum = 0.f;
#pragma unroll
    for (int i = 0; i < 16; ++i) { w[i] = __expf(w[i] - mx); ssum += w[i]; }
    const float inv = 1.f / ssum;

    const float* offp = off + (size_t)bq * 256 + h * 32;
    const float* refp = ref + (size_t)bq * 8;

    const int   Wl[4] = {128, 64, 32, 16};
    const int   ST[4] = {0, 16384, 20480, 21504};

    float acc = 0.f;
#pragma unroll
    for (int l = 0; l < 4; ++l) {
        const int   Wi = Wl[l];
        const float Wf = (float)Wi;
        const float rx = refp[l * 2 + 0];
        const float ry = refp[l * 2 + 1];
        const float* vbase = value + ((size_t)b * LENS + ST[l]) * CD + h * 32 + d;
#pragma unroll
        for (int p = 0; p < 4; ++p) {
            float ox = offp[l * 8 + p * 2 + 0];
            float oy = offp[l * 8 + p * 2 + 1];
            float lx = rx + ox / Wf;
            float ly = ry + oy / Wf;
            float x = lx * Wf - 0.5f;
            float y = ly * Wf - 0.5f;
            float x0f = floorf(x), y0f = floorf(y);
            int x0 = (int)x0f, y0 = (int)y0f;
            float wx = x - x0f, wy = y - y0f;
            float a = w[l * 4 + p] * inv;

            float c00 = 0.f, c10 = 0.f, c01 = 0.f, c11 = 0.f;
            bool xv0 = (x0 >= 0) & (x0 < Wi);
            bool xv1 = (x0 + 1 >= 0) & (x0 + 1 < Wi);
            bool yv0 = (y0 >= 0) & (y0 < Wi);
            bool yv1 = (y0 + 1 >= 0) & (y0 + 1 < Wi);
            if (xv0 & yv0) c00 = vbase[(size_t)(y0 * Wi + x0) * CD];
            if (xv1 & yv0) c10 = vbase[(size_t)(y0 * Wi + x0 + 1) * CD];
            if (xv0 & yv1) c01 = vbase[(size_t)((y0 + 1) * Wi + x0) * CD];
            if (xv1 & yv1) c11 = vbase[(size_t)((y0 + 1) * Wi + x0 + 1) * CD];
            float sv = (1.f - wx) * (1.f - wy) * c00 + wx * (1.f - wy) * c10
                     + (1.f - wx) * wy * c01 + wx * wy * c11;
            acc = fmaf(a, sv, acc);
        }
    }
    out[(size_t)bq * 256 + h * 32 + d] = acc;
}

// ---------------------------------------------------------------------------
// Fused residual + LayerNorm: out = LN(x + y) * g + b. One block per row.
// ---------------------------------------------------------------------------
__global__ __launch_bounds__(256) void ln_kernel(
    const float* __restrict__ x, const float* __restrict__ y,
    const float* __restrict__ g, const float* __restrict__ beta,
    float* __restrict__ out)
{
    const int r = blockIdx.x;
    const int c = threadIdx.x;
    float v = x[(size_t)r * 256 + c] + y[(size_t)r * 256 + c];
    float s1 = v, s2 = v * v;
#pragma unroll
    for (int msk = 32; msk; msk >>= 1) {
        s1 += __shfl_xor(s1, msk);
        s2 += __shfl_xor(s2, msk);
    }
    __shared__ float red[8];
    int w = c >> 6;
    if ((c & 63) == 0) { red[w] = s1; red[4 + w] = s2; }
    __syncthreads();
    s1 = red[0] + red[1] + red[2] + red[3];
    s2 = red[4] + red[5] + red[6] + red[7];
    float mean = s1 * (1.f / 256.f);
    float var  = s2 * (1.f / 256.f) - mean * mean;
    float inv  = 1.f / sqrtf(var + 1e-5f);
    out[(size_t)r * 256 + c] = (v - mean) * inv * g[c] + beta[c];
}

// ---------------------------------------------------------------------------
extern "C" void kernel_launch(void* const* d_in, const int* in_sizes, int n_in,
                              void* d_out, int out_size, void* d_ws, size_t ws_size,
                              hipStream_t stream)
{
    const float* tgt      = (const float*)d_in[0];
    const float* qpos     = (const float*)d_in[1];
    const float* refpts   = (const float*)d_in[2];
    const float* src      = (const float*)d_in[3];
    // d_in[4] src_spatial_shapes, d_in[5] level_start_index: compile-time constants
    const unsigned char* padmask = (const unsigned char*)d_in[6];
    const float* sa_in_w  = (const float*)d_in[7];
    const float* sa_in_b  = (const float*)d_in[8];
    const float* sa_out_w = (const float*)d_in[9];
    const float* sa_out_b = (const float*)d_in[10];
    const float* ca_off_w = (const float*)d_in[11];
    const float* ca_off_b = (const float*)d_in[12];
    const float* ca_aw_w  = (const float*)d_in[13];
    const float* ca_aw_b  = (const float*)d_in[14];
    const float* ca_val_w = (const float*)d_in[15];
    const float* ca_val_b = (const float*)d_in[16];
    const float* ca_out_w = (const float*)d_in[17];
    const float* ca_out_b = (const float*)d_in[18];
    const float* n1_g     = (const float*)d_in[19];
    const float* n1_b     = (const float*)d_in[20];
    const float* n2_g     = (const float*)d_in[21];
    const float* n2_b     = (const float*)d_in[22];
    const float* n3_g     = (const float*)d_in[23];
    const float* n3_b     = (const float*)d_in[24];
    const float* f1_w     = (const float*)d_in[25];
    const float* f1_b     = (const float*)d_in[26];
    const float* f2_w     = (const float*)d_in[27];
    const float* f2_b     = (const float*)d_in[28];
    float* out = (float*)d_out;

    float* ws = (float*)d_ws;
    size_t o = 0;
    auto alloc = [&](size_t n) { float* p = ws + o; o += n; return p; };
    float* bufA    = alloc((size_t)NQ * 1024);  // qkv (768 used), later FFN hidden
    float* buf_q   = alloc((size_t)NQ * 256);   // q = x + query_pos
    float* buf_o   = alloc((size_t)NQ * 256);   // attention / deform outputs
    float* buf_p   = alloc((size_t)NQ * 256);   // projection outputs
    float* buf_t1  = alloc((size_t)NQ * 256);
    float* buf_t2  = alloc((size_t)NQ * 256);
    float* buf_off = alloc((size_t)NQ * 256);
    float* buf_aw  = alloc((size_t)NQ * 128);
    float* buf_val = alloc((size_t)NV * 256);
    (void)ws_size; (void)n_in; (void)in_sizes; (void)out_size;

    dim3 blk(256);
    const int n4 = NQ * 256 / 4;        // 460800
    const int addg = (n4 + 255) / 256;  // 1800

    // ---- self-attention ----
    add_kernel<<<addg, blk, 0, stream>>>(tgt, qpos, buf_q, n4);
    gemm_nt<<<dim3(57, 8), blk, 0, stream>>>(buf_q, sa_in_w, sa_in_b, bufA, NQ, 256, 768, 0, nullptr);
    gemm_nt<<<dim3(57, 4), blk, 0, stream>>>(tgt, sa_in_w + 512 * 256, sa_in_b + 512, bufA + 512, NQ, 256, 768, 0, nullptr);
    attn_kernel<<<dim3(15, 8, 8), blk, 0, stream>>>(bufA, buf_o);
    gemm_nt<<<dim3(57, 4), blk, 0, stream>>>(buf_o, sa_out_w, sa_out_b, buf_p, NQ, 256, 256, 0, nullptr);
    ln_kernel<<<NQ, blk, 0, stream>>>(tgt, buf_p, n2_g, n2_b, buf_t1);

    // ---- deformable cross-attention ----
    add_kernel<<<addg, blk, 0, stream>>>(buf_t1, qpos, buf_q, n4);
    gemm_nt<<<dim3(1360, 4), blk, 0, stream>>>(src, ca_val_w, ca_val_b, buf_val, NV, 256, 256, 0, padmask);
    gemm_nt<<<dim3(57, 4), blk, 0, stream>>>(buf_q, ca_off_w, ca_off_b, buf_off, NQ, 256, 256, 0, nullptr);
    gemm_nt<<<dim3(57, 2), blk, 0, stream>>>(buf_q, ca_aw_w, ca_aw_b, buf_aw, NQ, 256, 128, 0, nullptr);
    deform_kernel<<<NQ, blk, 0, stream>>>(buf_val, buf_off, buf_aw, refpts, buf_o);
    gemm_nt<<<dim3(57, 4), blk, 0, stream>>>(buf_o, ca_out_w, ca_out_b, buf_p, NQ, 256, 256, 0, nullptr);
    ln_kernel<<<NQ, blk, 0, stream>>>(buf_t1, buf_p, n1_g, n1_b, buf_t2);

    // ---- FFN ----
    gemm_nt<<<dim3(57, 16), blk, 0, stream>>>(buf_t2, f1_w, f1_b, bufA, NQ, 256, 1024, 1, nullptr);
    gemm_nt<<<dim3(57, 4), blk, 0, stream>>>(bufA, f2_w, f2_b, buf_p, NQ, 1024, 256, 0, nullptr);
    ln_kernel<<<NQ, blk, 0, stream>>>(buf_t2, buf_p, n3_g, n3_b, out);
}

// Round 2
// 942.461 us; speedup vs baseline: 1.2848x; 1.2848x over previous
//
#include <hip/hip_runtime.h>
#include <cstdint>

constexpr int NB   = 8;
constexpr int LQn  = 900;
constexpr int CD   = 256;
constexpr int LENS = 21760;
constexpr int NQ   = NB * LQn;    // 7200
constexpr int NV   = NB * LENS;   // 174080

using short8 = __attribute__((ext_vector_type(8))) short;
using f32x4  = __attribute__((ext_vector_type(4))) float;

__device__ __forceinline__ ushort f2b(float x) {
    uint32_t u = __builtin_bit_cast(uint32_t, x);
    u += 0x7fffu + ((u >> 16) & 1u);
    return (ushort)(u >> 16);
}
__device__ __forceinline__ float b2f(ushort x) {
    uint32_t u = ((uint32_t)x) << 16;
    return __builtin_bit_cast(float, u);
}

// ---------------------------------------------------------------------------
// Weight conversion: 8 fp32 weight matrices -> one concatenated bf16 buffer.
// ---------------------------------------------------------------------------
struct WPtrs { const float* p[8]; };
// segment element offsets (all multiples of 4)
__constant__ const int kWOff[9] = {0, 196608, 262144, 327680, 360448, 425984,
                                   491520, 753664, 1015808};

__global__ __launch_bounds__(256) void cvt_w_kernel(WPtrs w, ushort* __restrict__ out) {
    int i = blockIdx.x * blockDim.x + threadIdx.x;   // float4 group
    int e = i * 4;
    if (e >= 1015808) return;
    int s = 0;
#pragma unroll
    for (int k = 1; k < 8; ++k) if (e >= kWOff[k]) s = k;
    float4 v = *reinterpret_cast<const float4*>(w.p[s] + (e - kWOff[s]));
    ushort4 o;
    o.x = f2b(v.x); o.y = f2b(v.y); o.z = f2b(v.z); o.w = f2b(v.w);
    *reinterpret_cast<ushort4*>(out + e) = o;
}

// q_bf = bf16(a+b); a_bf = bf16(a)
__global__ __launch_bounds__(256) void cvt_pair_kernel(
    const float* __restrict__ a, const float* __restrict__ b,
    ushort* __restrict__ sum_bf, ushort* __restrict__ a_bf, int n4) {
    int i = blockIdx.x * blockDim.x + threadIdx.x;
    if (i >= n4) return;
    float4 va = reinterpret_cast<const float4*>(a)[i];
    float4 vb = reinterpret_cast<const float4*>(b)[i];
    ushort4 s, t;
    s.x = f2b(va.x + vb.x); s.y = f2b(va.y + vb.y);
    s.z = f2b(va.z + vb.z); s.w = f2b(va.w + vb.w);
    reinterpret_cast<ushort4*>(sum_bf)[i] = s;
    if (a_bf) {
        t.x = f2b(va.x); t.y = f2b(va.y); t.z = f2b(va.z); t.w = f2b(va.w);
        reinterpret_cast<ushort4*>(a_bf)[i] = t;
    }
}

// ---------------------------------------------------------------------------
// MFMA GEMM: C[M x N] = A[M x K] * B[N x K]^T + bias.
// Tile 128x128, BK=32, 4 waves (2x2), each wave 64x64 = 4x4 16x16 frags.
// A: bf16 (global_load_lds direct) or f32 (reg-staged + converted).
// LDS chunk swizzle: chunk' = chunk ^ ((row>>1)&3)  (16B chunks, 64B rows).
// grid = (N/128, ceil(M/128)) -- x = column tile so A streams once.
// ---------------------------------------------------------------------------
template<bool A_F32, bool OUT_BF16, bool RELU, bool MASK>
__global__ __launch_bounds__(256) void gemm_mfma(
    const void* __restrict__ Av, const ushort* __restrict__ B,
    const float* __restrict__ bias, void* __restrict__ Cv,
    int M, int K, int ldc, const unsigned char* __restrict__ rowmask)
{
    __shared__ ushort As[4096];   // [128 rows][32 k] bf16, 64B rows
    __shared__ ushort Bs[4096];

    const int tid = threadIdx.x, lane = tid & 63, wave = tid >> 6;
    const int wr = wave >> 1, wc = wave & 1;
    const int bn = blockIdx.x * 128;
    const int bm = blockIdx.y * 128;
    const int lc15 = lane & 15, lk = lane >> 4;

    f32x4 acc[4][4] = {};

    int a_off[4], b_off[4];
#pragma unroll
    for (int fr = 0; fr < 4; ++fr) {
        int r = wr * 64 + fr * 16 + lc15;
        a_off[fr] = r * 32 + ((lk ^ ((r >> 1) & 3)) * 8);
        int rb = wc * 64 + fr * 16 + lc15;
        b_off[fr] = rb * 32 + ((lk ^ ((rb >> 1) & 3)) * 8);
    }

    for (int k0 = 0; k0 < K; k0 += 32) {
        // ---- stage A ----
        if constexpr (!A_F32) {
            const ushort* A = (const ushort*)Av;
#pragma unroll
            for (int t = 0; t < 2; ++t) {
                int row = wave * 32 + t * 16 + (lane >> 2);
                int p = lane & 3;
                int g = p ^ ((row >> 1) & 3);
                size_t ar = (size_t)bm + row; if (ar >= (size_t)M) ar = M - 1;
                const ushort* gp = A + ar * (size_t)K + k0 + g * 8;
                __builtin_amdgcn_global_load_lds(
                    (const __attribute__((address_space(1))) uint32_t*)gp,
                    (__attribute__((address_space(3))) uint32_t*)(As + (wave * 2 + t) * 512),
                    16, 0, 0);
            }
        } else {
            const float* A = (const float*)Av;
#pragma unroll
            for (int t = 0; t < 2; ++t) {
                int s = tid + t * 256;
                int row = s >> 2, p = s & 3;
                int g = p ^ ((row >> 1) & 3);
                size_t ar = (size_t)bm + row; if (ar >= (size_t)M) ar = M - 1;
                const float* gp = A + ar * (size_t)K + k0 + g * 8;
                float4 v0 = *reinterpret_cast<const float4*>(gp);
                float4 v1 = *reinterpret_cast<const float4*>(gp + 4);
                short8 pk;
                pk[0] = (short)f2b(v0.x); pk[1] = (short)f2b(v0.y);
                pk[2] = (short)f2b(v0.z); pk[3] = (short)f2b(v0.w);
                pk[4] = (short)f2b(v1.x); pk[5] = (short)f2b(v1.y);
                pk[6] = (short)f2b(v1.z); pk[7] = (short)f2b(v1.w);
                *reinterpret_cast<short8*>(&As[row * 32 + p * 8]) = pk;
            }
        }
        // ---- stage B (always bf16) ----
        {
#pragma unroll
            for (int t = 0; t < 2; ++t) {
                int row = wave * 32 + t * 16 + (lane >> 2);
                int p = lane & 3;
                int g = p ^ ((row >> 1) & 3);
                const ushort* gp = B + (size_t)(bn + row) * K + k0 + g * 8;
                __builtin_amdgcn_global_load_lds(
                    (const __attribute__((address_space(1))) uint32_t*)gp,
                    (__attribute__((address_space(3))) uint32_t*)(Bs + (wave * 2 + t) * 512),
                    16, 0, 0);
            }
        }
        __syncthreads();

        short8 af[4], bfr[4];
#pragma unroll
        for (int fr = 0; fr < 4; ++fr) af[fr]  = *reinterpret_cast<const short8*>(&As[a_off[fr]]);
#pragma unroll
        for (int fc = 0; fc < 4; ++fc) bfr[fc] = *reinterpret_cast<const short8*>(&Bs[b_off[fc]]);
#pragma unroll
        for (int fr = 0; fr < 4; ++fr)
#pragma unroll
            for (int fc = 0; fc < 4; ++fc)
                acc[fr][fc] = __builtin_amdgcn_mfma_f32_16x16x32_bf16(
                    af[fr], bfr[fc], acc[fr][fc], 0, 0, 0);
        __syncthreads();
    }

    // ---- epilogue ----
#pragma unroll
    for (int fc = 0; fc < 4; ++fc) {
        int col = bn + wc * 64 + fc * 16 + lc15;
        float bv = bias[col];
#pragma unroll
        for (int fr = 0; fr < 4; ++fr) {
            int rb = bm + wr * 64 + fr * 16 + lk * 4;
#pragma unroll
            for (int r = 0; r < 4; ++r) {
                int row = rb + r;
                if (row < M) {
                    float v = acc[fr][fc][r] + bv;
                    if constexpr (RELU) v = fmaxf(v, 0.f);
                    if constexpr (MASK) { if (rowmask[row]) v = 0.f; }
                    if constexpr (OUT_BF16)
                        ((ushort*)Cv)[(size_t)row * ldc + col] = f2b(v);
                    else
                        ((float*)Cv)[(size_t)row * ldc + col] = v;
                }
            }
        }
    }
}

// ---------------------------------------------------------------------------
// Flash self-attention, bf16 qkv input (NQ x 768), bf16 output (NQ x 256).
// fp32 math in LDS/registers. Block = (64-query tile, head, batch).
// ---------------------------------------------------------------------------
__global__ __launch_bounds__(256) void attn_kernel(
    const ushort* __restrict__ qkv, ushort* __restrict__ out)
{
    __shared__ float Qs[32][64];
    __shared__ float Ks[32][64];
    __shared__ float Vs[64][32];
    __shared__ float Ps[64][68];

    const int tid = threadIdx.x;
    const int tx = tid & 15;
    const int ty = tid >> 4;
    const int q0 = blockIdx.x * 64;
    const int h  = blockIdx.y;
    const int b  = blockIdx.z;
    const size_t base = (size_t)b * LQn * 768 + h * 32;
    const float sc = 0.17677669529663687f;

#pragma unroll
    for (int t = 0; t < 2; ++t) {
        int f = tid + t * 256;
        int row = f >> 3, c4 = (f & 7) * 4;
        int qr = q0 + row; if (qr > LQn - 1) qr = LQn - 1;
        ushort4 v = *reinterpret_cast<const ushort4*>(qkv + base + (size_t)qr * 768 + c4);
        Qs[c4 + 0][row] = b2f(v.x) * sc; Qs[c4 + 1][row] = b2f(v.y) * sc;
        Qs[c4 + 2][row] = b2f(v.z) * sc; Qs[c4 + 3][row] = b2f(v.w) * sc;
    }

    float m[4], l[4], acc[4][2];
#pragma unroll
    for (int i = 0; i < 4; ++i) { m[i] = -INFINITY; l[i] = 0.f; acc[i][0] = 0.f; acc[i][1] = 0.f; }

    for (int kb = 0; kb < LQn; kb += 64) {
        __syncthreads();
#pragma unroll
        for (int t = 0; t < 2; ++t) {
            int f = tid + t * 256;
            int row = f >> 3, c4 = (f & 7) * 4;
            int kr = kb + row;
            float kx, ky, kz, kw, vx, vy, vz, vw;
            if (kr < LQn) {
                ushort4 kv = *reinterpret_cast<const ushort4*>(qkv + base + (size_t)kr * 768 + 256 + c4);
                ushort4 vv = *reinterpret_cast<const ushort4*>(qkv + base + (size_t)kr * 768 + 512 + c4);
                kx = b2f(kv.x); ky = b2f(kv.y); kz = b2f(kv.z); kw = b2f(kv.w);
                vx = b2f(vv.x); vy = b2f(vv.y); vz = b2f(vv.z); vw = b2f(vv.w);
            } else { kx = ky = kz = kw = vx = vy = vz = vw = 0.f; }
            Ks[c4 + 0][row] = kx; Ks[c4 + 1][row] = ky;
            Ks[c4 + 2][row] = kz; Ks[c4 + 3][row] = kw;
            float4 vv4 = make_float4(vx, vy, vz, vw);
            *reinterpret_cast<float4*>(&Vs[row][c4]) = vv4;
        }
        __syncthreads();

        float s[4][4];
#pragma unroll
        for (int i = 0; i < 4; ++i)
#pragma unroll
            for (int j = 0; j < 4; ++j) s[i][j] = 0.f;
#pragma unroll
        for (int d = 0; d < 32; ++d) {
            float4 qa = *reinterpret_cast<const float4*>(&Qs[d][ty * 4]);
            float4 ka = *reinterpret_cast<const float4*>(&Ks[d][tx * 4]);
            float qm[4] = {qa.x, qa.y, qa.z, qa.w};
            float km[4] = {ka.x, ka.y, ka.z, ka.w};
#pragma unroll
            for (int i = 0; i < 4; ++i)
#pragma unroll
                for (int j = 0; j < 4; ++j)
                    s[i][j] = fmaf(qm[i], km[j], s[i][j]);
        }
        if (kb + 64 > LQn) {
#pragma unroll
            for (int j = 0; j < 4; ++j)
                if (kb + tx * 4 + j >= LQn) { s[0][j] = -INFINITY; s[1][j] = -INFINITY; s[2][j] = -INFINITY; s[3][j] = -INFINITY; }
        }

        float pv[4][4];
#pragma unroll
        for (int i = 0; i < 4; ++i) {
            float rm = fmaxf(fmaxf(s[i][0], s[i][1]), fmaxf(s[i][2], s[i][3]));
            rm = fmaxf(rm, __shfl_xor(rm, 1));
            rm = fmaxf(rm, __shfl_xor(rm, 2));
            rm = fmaxf(rm, __shfl_xor(rm, 4));
            rm = fmaxf(rm, __shfl_xor(rm, 8));
            float mn = fmaxf(m[i], rm);
            float esc = __expf(m[i] - mn);
            float rs = 0.f;
#pragma unroll
            for (int j = 0; j < 4; ++j) { pv[i][j] = __expf(s[i][j] - mn); rs += pv[i][j]; }
            rs += __shfl_xor(rs, 1); rs += __shfl_xor(rs, 2);
            rs += __shfl_xor(rs, 4); rs += __shfl_xor(rs, 8);
            l[i] = l[i] * esc + rs;
            m[i] = mn;
            acc[i][0] *= esc; acc[i][1] *= esc;
        }
#pragma unroll
        for (int i = 0; i < 4; ++i)
#pragma unroll
            for (int j = 0; j < 4; ++j)
                Ps[tx * 4 + j][ty * 4 + i] = pv[i][j];
        __syncthreads();
#pragma unroll
        for (int k = 0; k < 64; ++k) {
            float4 p4 = *reinterpret_cast<const float4*>(&Ps[k][ty * 4]);
            float2 v2 = *reinterpret_cast<const float2*>(&Vs[k][tx * 2]);
            float pa[4] = {p4.x, p4.y, p4.z, p4.w};
#pragma unroll
            for (int i = 0; i < 4; ++i) {
                acc[i][0] = fmaf(pa[i], v2.x, acc[i][0]);
                acc[i][1] = fmaf(pa[i], v2.y, acc[i][1]);
            }
        }
    }

#pragma unroll
    for (int i = 0; i < 4; ++i) {
        int qr = q0 + ty * 4 + i;
        if (qr < LQn) {
            float invl = 1.f / l[i];
            ushort2 o;
            o.x = f2b(acc[i][0] * invl);
            o.y = f2b(acc[i][1] * invl);
            *reinterpret_cast<ushort2*>(out + ((size_t)b * LQn + qr) * CD + h * 32 + tx * 2) = o;
        }
    }
}

// ---------------------------------------------------------------------------
// Deformable sampling, bf16 value table, bf16 output.
// ---------------------------------------------------------------------------
__global__ __launch_bounds__(256) void deform_kernel(
    const ushort* __restrict__ value,  // (NB, LENS, 256) bf16
    const float* __restrict__ off,     // (NQ, 256)
    const float* __restrict__ aw,      // (NQ, 128)
    const float* __restrict__ ref,     // (NB, LQ, NL, 2)
    ushort* __restrict__ out)          // (NQ, 256) bf16
{
    const int grp = (blockIdx.x << 3) + (threadIdx.x >> 5);
    const int d   = threadIdx.x & 31;
    const int h   = grp & 7;
    const int bq  = grp >> 3;
    const int b   = bq / LQn;

    const float* awp = aw + (size_t)bq * 128 + h * 16;
    float w[16]; float mx = -1e30f;
#pragma unroll
    for (int i = 0; i < 16; ++i) { w[i] = awp[i]; mx = fmaxf(mx, w[i]); }
    float ssum = 0.f;
#pragma unroll
    for (int i = 0; i < 16; ++i) { w[i] = __expf(w[i] - mx); ssum += w[i]; }
    const float inv = 1.f / ssum;

    const float* offp = off + (size_t)bq * 256 + h * 32;
    const float* refp = ref + (size_t)bq * 8;

    const int Wl[4] = {128, 64, 32, 16};
    const int ST[4] = {0, 16384, 20480, 21504};

    float acc = 0.f;
#pragma unroll
    for (int l = 0; l < 4; ++l) {
        const int   Wi = Wl[l];
        const float Wf = (float)Wi;
        const float rx = refp[l * 2 + 0];
        const float ry = refp[l * 2 + 1];
        const ushort* vbase = value + ((size_t)b * LENS + ST[l]) * CD + h * 32 + d;
#pragma unroll
        for (int p = 0; p < 4; ++p) {
            float ox = offp[l * 8 + p * 2 + 0];
            float oy = offp[l * 8 + p * 2 + 1];
            float x = (rx + ox / Wf) * Wf - 0.5f;
            float y = (ry + oy / Wf) * Wf - 0.5f;
            float x0f = floorf(x), y0f = floorf(y);
            int x0 = (int)x0f, y0 = (int)y0f;
            float wx = x - x0f, wy = y - y0f;
            float a = w[l * 4 + p] * inv;

            float c00 = 0.f, c10 = 0.f, c01 = 0.f, c11 = 0.f;
            bool xv0 = (x0 >= 0) & (x0 < Wi);
            bool xv1 = (x0 + 1 >= 0) & (x0 + 1 < Wi);
            bool yv0 = (y0 >= 0) & (y0 < Wi);
            bool yv1 = (y0 + 1 >= 0) & (y0 + 1 < Wi);
            if (xv0 & yv0) c00 = b2f(vbase[(size_t)(y0 * Wi + x0) * CD]);
            if (xv1 & yv0) c10 = b2f(vbase[(size_t)(y0 * Wi + x0 + 1) * CD]);
            if (xv0 & yv1) c01 = b2f(vbase[(size_t)((y0 + 1) * Wi + x0) * CD]);
            if (xv1 & yv1) c11 = b2f(vbase[(size_t)((y0 + 1) * Wi + x0 + 1) * CD]);
            float sv = (1.f - wx) * (1.f - wy) * c00 + wx * (1.f - wy) * c10
                     + (1.f - wx) * wy * c01 + wx * wy * c11;
            acc = fmaf(a, sv, acc);
        }
    }
    out[(size_t)bq * 256 + h * 32 + d] = f2b(acc);
}

// ---------------------------------------------------------------------------
// Fused residual + LayerNorm. Optional secondary bf16 output.
// ---------------------------------------------------------------------------
__global__ __launch_bounds__(256) void ln_kernel(
    const float* __restrict__ x, const float* __restrict__ y,
    const float* __restrict__ g, const float* __restrict__ beta,
    float* __restrict__ out, ushort* __restrict__ out_bf)
{
    const int r = blockIdx.x;
    const int c = threadIdx.x;
    float v = x[(size_t)r * 256 + c] + y[(size_t)r * 256 + c];
    float s1 = v, s2 = v * v;
#pragma unroll
    for (int msk = 32; msk; msk >>= 1) {
        s1 += __shfl_xor(s1, msk);
        s2 += __shfl_xor(s2, msk);
    }
    __shared__ float red[8];
    int w = c >> 6;
    if ((c & 63) == 0) { red[w] = s1; red[4 + w] = s2; }
    __syncthreads();
    s1 = red[0] + red[1] + red[2] + red[3];
    s2 = red[4] + red[5] + red[6] + red[7];
    float mean = s1 * (1.f / 256.f);
    float var  = s2 * (1.f / 256.f) - mean * mean;
    float inv  = 1.f / sqrtf(var + 1e-5f);
    float o = (v - mean) * inv * g[c] + beta[c];
    out[(size_t)r * 256 + c] = o;
    if (out_bf) out_bf[(size_t)r * 256 + c] = f2b(o);
}

// ---------------------------------------------------------------------------
extern "C" void kernel_launch(void* const* d_in, const int* in_sizes, int n_in,
                              void* d_out, int out_size, void* d_ws, size_t ws_size,
                              hipStream_t stream)
{
    const float* tgt      = (const float*)d_in[0];
    const float* qpos     = (const float*)d_in[1];
    const float* refpts   = (const float*)d_in[2];
    const float* src      = (const float*)d_in[3];
    const unsigned char* padmask = (const unsigned char*)d_in[6];
    const float* sa_in_w  = (const float*)d_in[7];
    const float* sa_in_b  = (const float*)d_in[8];
    const float* sa_out_w = (const float*)d_in[9];
    const float* sa_out_b = (const float*)d_in[10];
    const float* ca_off_w = (const float*)d_in[11];
    const float* ca_off_b = (const float*)d_in[12];
    const float* ca_aw_w  = (const float*)d_in[13];
    const float* ca_aw_b  = (const float*)d_in[14];
    const float* ca_val_w = (const float*)d_in[15];
    const float* ca_val_b = (const float*)d_in[16];
    const float* ca_out_w = (const float*)d_in[17];
    const float* ca_out_b = (const float*)d_in[18];
    const float* n1_g     = (const float*)d_in[19];
    const float* n1_b     = (const float*)d_in[20];
    const float* n2_g     = (const float*)d_in[21];
    const float* n2_b     = (const float*)d_in[22];
    const float* n3_g     = (const float*)d_in[23];
    const float* n3_b     = (const float*)d_in[24];
    const float* f1_w     = (const float*)d_in[25];
    const float* f1_b     = (const float*)d_in[26];
    const float* f2_w     = (const float*)d_in[27];
    const float* f2_b     = (const float*)d_in[28];
    float* out = (float*)d_out;
    (void)in_sizes; (void)n_in; (void)out_size; (void)ws_size;

    // ---- workspace layout ----
    float* ws = (float*)d_ws;
    size_t fo = 0;
    auto fa = [&](size_t n) { float* p = ws + fo; fo += n; return p; };
    float* buf_p  = fa((size_t)NQ * 256);
    float* t1     = fa((size_t)NQ * 256);
    float* t2     = fa((size_t)NQ * 256);
    float* off_f  = fa((size_t)NQ * 256);
    float* aw_f   = fa((size_t)NQ * 128);
    ushort* ub = (ushort*)(ws + fo);
    size_t uo = 0;
    auto ua = [&](size_t n) { ushort* p = ub + uo; uo += n; return p; };
    ushort* w_bf    = ua(1015808);
    ushort* q_bf    = ua((size_t)NQ * 256);
    ushort* tgt_bf  = ua((size_t)NQ * 256);
    ushort* q2_bf   = ua((size_t)NQ * 256);
    ushort* qkv_bf  = ua((size_t)NQ * 768);
    ushort* attn_bf = ua((size_t)NQ * 256);
    ushort* dfo_bf  = ua((size_t)NQ * 256);
    ushort* t2_bf   = ua((size_t)NQ * 256);
    ushort* hid_bf  = ua((size_t)NQ * 1024);
    ushort* val_bf  = ua((size_t)NV * 256);

    const ushort* w_sa_in  = w_bf + 0;
    const ushort* w_sa_out = w_bf + 196608;
    const ushort* w_ca_off = w_bf + 262144;
    const ushort* w_ca_aw  = w_bf + 327680;
    const ushort* w_ca_val = w_bf + 360448;
    const ushort* w_ca_out = w_bf + 425984;
    const ushort* w_f1     = w_bf + 491520;
    const ushort* w_f2     = w_bf + 753664;

    dim3 blk(256);
    const int n4 = NQ * 256 / 4;       // 460800
    const int cg = (n4 + 255) / 256;   // 1800

    // ---- weight conversion ----
    WPtrs wp;
    wp.p[0] = sa_in_w; wp.p[1] = sa_out_w; wp.p[2] = ca_off_w; wp.p[3] = ca_aw_w;
    wp.p[4] = ca_val_w; wp.p[5] = ca_out_w; wp.p[6] = f1_w; wp.p[7] = f2_w;
    cvt_w_kernel<<<992, blk, 0, stream>>>(wp, w_bf);

    // ---- self-attention ----
    cvt_pair_kernel<<<cg, blk, 0, stream>>>(tgt, qpos, q_bf, tgt_bf, n4);
    gemm_mfma<false, true, false, false><<<dim3(4, 57), blk, 0, stream>>>(
        q_bf, w_sa_in, sa_in_b, qkv_bf, NQ, 256, 768, nullptr);
    gemm_mfma<false, true, false, false><<<dim3(2, 57), blk, 0, stream>>>(
        tgt_bf, w_sa_in + 512 * 256, sa_in_b + 512, qkv_bf + 512, NQ, 256, 768, nullptr);
    attn_kernel<<<dim3(15, 8, 8), blk, 0, stream>>>(qkv_bf, attn_bf);
    gemm_mfma<false, false, false, false><<<dim3(2, 57), blk, 0, stream>>>(
        attn_bf, w_sa_out, sa_out_b, buf_p, NQ, 256, 256, nullptr);
    ln_kernel<<<NQ, blk, 0, stream>>>(tgt, buf_p, n2_g, n2_b, t1, nullptr);

    // ---- deformable cross-attention ----
    cvt_pair_kernel<<<cg, blk, 0, stream>>>(t1, qpos, q2_bf, nullptr, n4);
    gemm_mfma<true, true, false, true><<<dim3(2, 1360), blk, 0, stream>>>(
        src, w_ca_val, ca_val_b, val_bf, NV, 256, 256, padmask);
    gemm_mfma<false, false, false, false><<<dim3(2, 57), blk, 0, stream>>>(
        q2_bf, w_ca_off, ca_off_b, off_f, NQ, 256, 256, nullptr);
    gemm_mfma<false, false, false, false><<<dim3(1, 57), blk, 0, stream>>>(
        q2_bf, w_ca_aw, ca_aw_b, aw_f, NQ, 256, 128, nullptr);
    deform_kernel<<<NQ, blk, 0, stream>>>(val_bf, off_f, aw_f, refpts, dfo_bf);
    gemm_mfma<false, false, false, false><<<dim3(2, 57), blk, 0, stream>>>(
        dfo_bf, w_ca_out, ca_out_b, buf_p, NQ, 256, 256, nullptr);
    ln_kernel<<<NQ, blk, 0, stream>>>(t1, buf_p, n1_g, n1_b, t2, t2_bf);

    // ---- FFN ----
    gemm_mfma<false, true, true, false><<<dim3(8, 57), blk, 0, stream>>>(
        t2_bf, w_f1, f1_b, hid_bf, NQ, 256, 1024, nullptr);
    gemm_mfma<false, false, false, false><<<dim3(2, 57), blk, 0, stream>>>(
        hid_bf, w_f2, f2_b, buf_p, NQ, 1024, 256, nullptr);
    ln_kernel<<<NQ, blk, 0, stream>>>(t2, buf_p, n3_g, n3_b, out, nullptr);
}

// Round 4
// 582.571 us; speedup vs baseline: 2.0786x; 1.6178x over previous
//
#include <hip/hip_runtime.h>
#include <cstdint>

constexpr int NB   = 8;
constexpr int LQn  = 900;
constexpr int CD   = 256;
constexpr int LENS = 21760;
constexpr int NQ   = NB * LQn;    // 7200
constexpr int NV   = NB * LENS;   // 174080

using short8 = __attribute__((ext_vector_type(8))) short;
using f32x4  = __attribute__((ext_vector_type(4))) float;

__device__ __forceinline__ ushort f2b(float x) {
    uint32_t u = __builtin_bit_cast(uint32_t, x);
    u += 0x7fffu + ((u >> 16) & 1u);
    return (ushort)(u >> 16);
}
__device__ __forceinline__ float b2f(ushort x) {
    uint32_t u = ((uint32_t)x) << 16;
    return __builtin_bit_cast(float, u);
}
__device__ __forceinline__ float b2f_lo(uint32_t u) {
    return __builtin_bit_cast(float, u << 16);
}
__device__ __forceinline__ float b2f_hi(uint32_t u) {
    return __builtin_bit_cast(float, u & 0xffff0000u);
}

// ---------------------------------------------------------------------------
// Weight conversion + bias concat for the fused off/aw projection.
// ---------------------------------------------------------------------------
struct WPtrs { const float* p[8]; };
__constant__ const int kWOff[9] = {0, 196608, 262144, 327680, 360448, 425984,
                                   491520, 753664, 1015808};

__global__ __launch_bounds__(256) void cvt_w_kernel(
    WPtrs w, ushort* __restrict__ out,
    const float* __restrict__ offb, const float* __restrict__ awb,
    float* __restrict__ biascat)
{
    if (blockIdx.x == 992) {
        int t = threadIdx.x;
        if (t < 384) biascat[t] = t < 256 ? offb[t] : awb[t - 256];
        return;
    }
    int i = blockIdx.x * blockDim.x + threadIdx.x;
    int e = i * 4;
    int s = 0;
#pragma unroll
    for (int k = 1; k < 8; ++k) if (e >= kWOff[k]) s = k;
    float4 v = *reinterpret_cast<const float4*>(w.p[s] + (e - kWOff[s]));
    ushort4 o;
    o.x = f2b(v.x); o.y = f2b(v.y); o.z = f2b(v.z); o.w = f2b(v.w);
    *reinterpret_cast<ushort4*>(out + e) = o;
}

__global__ __launch_bounds__(256) void cvt_pair_kernel(
    const float* __restrict__ a, const float* __restrict__ b,
    ushort* __restrict__ sum_bf, ushort* __restrict__ a_bf, int n4) {
    int i = blockIdx.x * blockDim.x + threadIdx.x;
    if (i >= n4) return;
    float4 va = reinterpret_cast<const float4*>(a)[i];
    float4 vb = reinterpret_cast<const float4*>(b)[i];
    ushort4 s, t;
    s.x = f2b(va.x + vb.x); s.y = f2b(va.y + vb.y);
    s.z = f2b(va.z + vb.z); s.w = f2b(va.w + vb.w);
    reinterpret_cast<ushort4*>(sum_bf)[i] = s;
    t.x = f2b(va.x); t.y = f2b(va.y); t.z = f2b(va.z); t.w = f2b(va.w);
    reinterpret_cast<ushort4*>(a_bf)[i] = t;
}

// ---------------------------------------------------------------------------
// MFMA GEMM: C[M x N] = A[M x K] * B[N x K]^T + bias.
// BM x 128 tile, BK=32, 4 waves (2x2). OUTK: 0=f32, 1=bf16, 2=bf16 val-transposed.
// ---------------------------------------------------------------------------
template<int BM, bool A_F32, int OUTK, bool RELU, bool MASK>
__global__ __launch_bounds__(256) void gemm_mfma(
    const void* __restrict__ Av, const ushort* __restrict__ B,
    const float* __restrict__ bias, void* __restrict__ Cv,
    int M, int K, int ldc, const unsigned char* __restrict__ rowmask)
{
    constexpr int RIT = BM / 64;   // A staging iterations
    constexpr int FR  = BM / 32;   // M frags per wave
    __shared__ ushort As[BM * 32];
    __shared__ ushort Bs[4096];

    const int tid = threadIdx.x, lane = tid & 63, wave = tid >> 6;
    const int wr = wave >> 1, wc = wave & 1;
    const int bn = blockIdx.x * 128;
    const int bm = blockIdx.y * BM;
    const int lc15 = lane & 15, lk = lane >> 4;

    f32x4 acc[FR][4] = {};

    int a_off[FR], b_off[4];
#pragma unroll
    for (int fr = 0; fr < FR; ++fr) {
        int r = wr * (BM / 2) + fr * 16 + lc15;
        a_off[fr] = r * 32 + ((lk ^ ((r >> 1) & 3)) * 8);
    }
#pragma unroll
    for (int fc = 0; fc < 4; ++fc) {
        int rb = wc * 64 + fc * 16 + lc15;
        b_off[fc] = rb * 32 + ((lk ^ ((rb >> 1) & 3)) * 8);
    }

    for (int k0 = 0; k0 < K; k0 += 32) {
        if constexpr (!A_F32) {
            const ushort* A = (const ushort*)Av;
#pragma unroll
            for (int t = 0; t < RIT; ++t) {
                int row = wave * (16 * RIT) + t * 16 + (lane >> 2);
                int p = lane & 3;
                int g = p ^ ((row >> 1) & 3);
                size_t ar = (size_t)bm + row; if (ar >= (size_t)M) ar = M - 1;
                const ushort* gp = A + ar * (size_t)K + k0 + g * 8;
                __builtin_amdgcn_global_load_lds(
                    (const __attribute__((address_space(1))) uint32_t*)gp,
                    (__attribute__((address_space(3))) uint32_t*)(As + (wave * RIT + t) * 512),
                    16, 0, 0);
            }
        } else {
            const float* A = (const float*)Av;
#pragma unroll
            for (int t = 0; t < RIT; ++t) {
                int s = tid + t * 256;
                int row = s >> 2, p = s & 3;
                int g = p ^ ((row >> 1) & 3);
                size_t ar = (size_t)bm + row; if (ar >= (size_t)M) ar = M - 1;
                const float* gp = A + ar * (size_t)K + k0 + g * 8;
                float4 v0 = *reinterpret_cast<const float4*>(gp);
                float4 v1 = *reinterpret_cast<const float4*>(gp + 4);
                short8 pk;
                pk[0] = (short)f2b(v0.x); pk[1] = (short)f2b(v0.y);
                pk[2] = (short)f2b(v0.z); pk[3] = (short)f2b(v0.w);
                pk[4] = (short)f2b(v1.x); pk[5] = (short)f2b(v1.y);
                pk[6] = (short)f2b(v1.z); pk[7] = (short)f2b(v1.w);
                *reinterpret_cast<short8*>(&As[row * 32 + p * 8]) = pk;
            }
        }
        {
#pragma unroll
            for (int t = 0; t < 2; ++t) {
                int row = wave * 32 + t * 16 + (lane >> 2);
                int p = lane & 3;
                int g = p ^ ((row >> 1) & 3);
                const ushort* gp = B + (size_t)(bn + row) * K + k0 + g * 8;
                __builtin_amdgcn_global_load_lds(
                    (const __attribute__((address_space(1))) uint32_t*)gp,
                    (__attribute__((address_space(3))) uint32_t*)(Bs + (wave * 2 + t) * 512),
                    16, 0, 0);
            }
        }
        __syncthreads();

        short8 af[FR], bfr[4];
#pragma unroll
        for (int fr = 0; fr < FR; ++fr) af[fr]  = *reinterpret_cast<const short8*>(&As[a_off[fr]]);
#pragma unroll
        for (int fc = 0; fc < 4; ++fc) bfr[fc] = *reinterpret_cast<const short8*>(&Bs[b_off[fc]]);
#pragma unroll
        for (int fr = 0; fr < FR; ++fr)
#pragma unroll
            for (int fc = 0; fc < 4; ++fc)
                acc[fr][fc] = __builtin_amdgcn_mfma_f32_16x16x32_bf16(
                    af[fr], bfr[fc], acc[fr][fc], 0, 0, 0);
        __syncthreads();
    }

#pragma unroll
    for (int fc = 0; fc < 4; ++fc) {
        int col = bn + wc * 64 + fc * 16 + lc15;
        float bv = bias[col];
#pragma unroll
        for (int fr = 0; fr < FR; ++fr) {
            int rb = bm + wr * (BM / 2) + fr * 16 + lk * 4;
#pragma unroll
            for (int r = 0; r < 4; ++r) {
                int row = rb + r;
                if (row < M) {
                    float v = acc[fr][fc][r] + bv;
                    if constexpr (RELU) v = fmaxf(v, 0.f);
                    if constexpr (MASK) { if (rowmask[row]) v = 0.f; }
                    if constexpr (OUTK == 0)
                        ((float*)Cv)[(size_t)row * ldc + col] = v;
                    else if constexpr (OUTK == 1)
                        ((ushort*)Cv)[(size_t)row * ldc + col] = f2b(v);
                    else {
                        int brow = row / LENS;
                        int len  = row - brow * LENS;
                        int hh = col >> 5, ch = col & 31;
                        ((ushort*)Cv)[((size_t)(brow * 8 + hh) * LENS + len) * 32 + ch] = f2b(v);
                    }
                }
            }
        }
    }
}

// ---------------------------------------------------------------------------
// MFMA flash self-attention. Block = (64-q tile, h, b), 4 waves, each wave
// owns 16 queries. QK^T and PV via 16x16x32 bf16 MFMA (dh=32 = one K-step).
// ---------------------------------------------------------------------------
__global__ __launch_bounds__(256) void attn_mfma(
    const ushort* __restrict__ qkv, ushort* __restrict__ out)
{
    __shared__ ushort Vt[32][72];        // [dh][key], 144B row stride
    __shared__ ushort Plds[4][16][72];   // per-wave P [q][key]

    const int tid = threadIdx.x, lane = tid & 63, wave = tid >> 6;
    const int lq = lane & 15, lg = lane >> 4;
    const int q0 = blockIdx.x * 64;
    const int h = blockIdx.y, b = blockIdx.z;
    const size_t bbase = (size_t)b * LQn * 768;

    int qrow = q0 + wave * 16 + lq; if (qrow > LQn - 1) qrow = LQn - 1;
    short8 aq = *reinterpret_cast<const short8*>(
        qkv + bbase + (size_t)qrow * 768 + h * 32 + lg * 8);

    f32x4 accO[2] = {};
    float m[4], l[4];
#pragma unroll
    for (int r = 0; r < 4; ++r) { m[r] = -3.0e38f; l[r] = 0.f; }

    for (int kt = 0; kt < 15; ++kt) {
        const int kb = kt * 64;
        __syncthreads();
        {   // stage V transposed: thread -> (key = tid>>2, dh chunk = (tid&3)*8)
            int key = tid >> 2, dhc = (tid & 3) * 8;
            int kg = kb + key; if (kg > LQn - 1) kg = LQn - 1;
            short8 vv = *reinterpret_cast<const short8*>(
                qkv + bbase + (size_t)kg * 768 + 512 + h * 32 + dhc);
#pragma unroll
            for (int j = 0; j < 8; ++j) Vt[dhc + j][key] = (ushort)vv[j];
        }
        __syncthreads();

        f32x4 s4[4];
#pragma unroll
        for (int fc = 0; fc < 4; ++fc) {
            int krow = kb + fc * 16 + lq;
            int kc = krow > LQn - 1 ? LQn - 1 : krow;
            short8 bk = *reinterpret_cast<const short8*>(
                qkv + bbase + (size_t)kc * 768 + 256 + h * 32 + lg * 8);
            f32x4 z = {};
            s4[fc] = __builtin_amdgcn_mfma_f32_16x16x32_bf16(aq, bk, z, 0, 0, 0);
            bool inval = krow >= LQn;
#pragma unroll
            for (int r = 0; r < 4; ++r)
                s4[fc][r] = inval ? -3.0e38f : s4[fc][r] * 0.17677669529663687f;
        }

#pragma unroll
        for (int r = 0; r < 4; ++r) {
            float rm = fmaxf(fmaxf(s4[0][r], s4[1][r]), fmaxf(s4[2][r], s4[3][r]));
            rm = fmaxf(rm, __shfl_xor(rm, 1));
            rm = fmaxf(rm, __shfl_xor(rm, 2));
            rm = fmaxf(rm, __shfl_xor(rm, 4));
            rm = fmaxf(rm, __shfl_xor(rm, 8));
            float mn = fmaxf(m[r], rm);
            float esc = __expf(m[r] - mn);
            float rs = 0.f;
#pragma unroll
            for (int fc = 0; fc < 4; ++fc) {
                float p = __expf(s4[fc][r] - mn);
                s4[fc][r] = p; rs += p;
            }
            rs += __shfl_xor(rs, 1); rs += __shfl_xor(rs, 2);
            rs += __shfl_xor(rs, 4); rs += __shfl_xor(rs, 8);
            m[r] = mn;
            l[r] = l[r] * esc + rs;
            accO[0][r] *= esc; accO[1][r] *= esc;
        }

#pragma unroll
        for (int fc = 0; fc < 4; ++fc)
#pragma unroll
            for (int r = 0; r < 4; ++r)
                Plds[wave][lg * 4 + r][fc * 16 + lq] = f2b(s4[fc][r]);

#pragma unroll
        for (int ks = 0; ks < 2; ++ks) {
            short8 ap = *reinterpret_cast<const short8*>(&Plds[wave][lq][ks * 32 + lg * 8]);
#pragma unroll
            for (int fc = 0; fc < 2; ++fc) {
                short8 bv = *reinterpret_cast<const short8*>(&Vt[fc * 16 + lq][ks * 32 + lg * 8]);
                accO[fc] = __builtin_amdgcn_mfma_f32_16x16x32_bf16(ap, bv, accO[fc], 0, 0, 0);
            }
        }
    }

#pragma unroll
    for (int r = 0; r < 4; ++r) {
        int q = q0 + wave * 16 + lg * 4 + r;
        if (q < LQn) {
            float invl = 1.f / l[r];
#pragma unroll
            for (int fc = 0; fc < 2; ++fc)
                out[((size_t)b * LQn + q) * 256 + h * 32 + fc * 16 + lq] =
                    f2b(accO[fc][r] * invl);
        }
    }
}

// ---------------------------------------------------------------------------
// Deformable sampling v2: value in (b, h, LENS, 32) layout; 16 lanes per
// (bq,h) group, 2 channels/lane; params computed by lane=sample, staged in LDS.
// ---------------------------------------------------------------------------
__global__ __launch_bounds__(256) void deform2_kernel(
    const ushort* __restrict__ valt,   // (NB*8, LENS, 32) bf16
    const float* __restrict__ offaw,   // (NQ, 384): [0:256) off, [256:384) aw
    const float* __restrict__ ref,     // (NB, LQ, NL, 2)
    ushort* __restrict__ out)          // (NQ, 256) bf16
{
    __shared__ int   Pi[16][16][4];
    __shared__ float Pw[16][16][4];

    const int tid = threadIdx.x;
    const int grp = tid >> 4;          // 0..15
    const int lane = tid & 15;
    const int gg = blockIdx.x * 16 + grp;     // 0..57599, h-major
    const int h  = gg / 7200;
    const int bq = gg - h * 7200;
    const int b  = bq / LQn;

    const float* row = offaw + (size_t)bq * 384;
    // ---- per-lane sample params (lane = sample s = l*4+p) ----
    float aval = row[256 + h * 16 + lane];
    float mx = aval;
    mx = fmaxf(mx, __shfl_xor(mx, 1));
    mx = fmaxf(mx, __shfl_xor(mx, 2));
    mx = fmaxf(mx, __shfl_xor(mx, 4));
    mx = fmaxf(mx, __shfl_xor(mx, 8));
    float e = __expf(aval - mx);
    float se = e;
    se += __shfl_xor(se, 1); se += __shfl_xor(se, 2);
    se += __shfl_xor(se, 4); se += __shfl_xor(se, 8);
    float a = e / se;

    const int lv = lane >> 2;
    const int W = 128 >> lv;
    const int STl[4] = {0, 16384, 20480, 21504};
    const float Wf = (float)W;
    float2 off2 = *reinterpret_cast<const float2*>(row + h * 32 + lane * 2);
    float rx = ref[(size_t)bq * 8 + lv * 2];
    float ry = ref[(size_t)bq * 8 + lv * 2 + 1];
    float x = (rx + off2.x / Wf) * Wf - 0.5f;
    float y = (ry + off2.y / Wf) * Wf - 0.5f;
    float x0f = floorf(x), y0f = floorf(y);
    int x0 = (int)x0f, y0 = (int)y0f;
    float wx = x - x0f, wy = y - y0f;
    float vx0 = (x0 >= 0 && x0 < W) ? 1.f : 0.f;
    float vx1 = (x0 + 1 >= 0 && x0 + 1 < W) ? 1.f : 0.f;
    float vy0 = (y0 >= 0 && y0 < W) ? 1.f : 0.f;
    float vy1 = (y0 + 1 >= 0 && y0 + 1 < W) ? 1.f : 0.f;
    int x0c = min(max(x0, 0), W - 1), x1c = min(max(x0 + 1, 0), W - 1);
    int y0c = min(max(y0, 0), W - 1), y1c = min(max(y0 + 1, 0), W - 1);
    int base = STl[lv];
    Pi[grp][lane][0] = base + y0c * W + x0c;
    Pi[grp][lane][1] = base + y0c * W + x1c;
    Pi[grp][lane][2] = base + y1c * W + x0c;
    Pi[grp][lane][3] = base + y1c * W + x1c;
    Pw[grp][lane][0] = (1.f - wx) * (1.f - wy) * vx0 * vy0 * a;
    Pw[grp][lane][1] = wx * (1.f - wy) * vx1 * vy0 * a;
    Pw[grp][lane][2] = (1.f - wx) * wy * vx0 * vy1 * a;
    Pw[grp][lane][3] = wx * wy * vx1 * vy1 * a;

    // groups are wave-private (4 groups per wave) -> no __syncthreads needed
    const ushort* vb = valt + (size_t)(b * 8 + h) * (LENS * 32);
    float accx = 0.f, accy = 0.f;
#pragma unroll 4
    for (int s = 0; s < 16; ++s) {
        int4  idx = *reinterpret_cast<const int4*>(Pi[grp][s]);
        float4 w  = *reinterpret_cast<const float4*>(Pw[grp][s]);
        uint32_t u00 = *reinterpret_cast<const uint32_t*>(vb + idx.x * 32 + lane * 2);
        uint32_t u10 = *reinterpret_cast<const uint32_t*>(vb + idx.y * 32 + lane * 2);
        uint32_t u01 = *reinterpret_cast<const uint32_t*>(vb + idx.z * 32 + lane * 2);
        uint32_t u11 = *reinterpret_cast<const uint32_t*>(vb + idx.w * 32 + lane * 2);
        accx = fmaf(w.x, b2f_lo(u00), accx); accy = fmaf(w.x, b2f_hi(u00), accy);
        accx = fmaf(w.y, b2f_lo(u10), accx); accy = fmaf(w.y, b2f_hi(u10), accy);
        accx = fmaf(w.z, b2f_lo(u01), accx); accy = fmaf(w.z, b2f_hi(u01), accy);
        accx = fmaf(w.w, b2f_lo(u11), accx); accy = fmaf(w.w, b2f_hi(u11), accy);
    }
    uint32_t pack = ((uint32_t)f2b(accy) << 16) | (uint32_t)f2b(accx);
    *reinterpret_cast<uint32_t*>(out + (size_t)bq * 256 + h * 32 + lane * 2) = pack;
}

// ---------------------------------------------------------------------------
// Fused residual + LayerNorm; optional bf16 copy and bf16(x+qpos) output.
// ---------------------------------------------------------------------------
__global__ __launch_bounds__(256) void ln_kernel(
    const float* __restrict__ x, const float* __restrict__ y,
    const float* __restrict__ g, const float* __restrict__ beta,
    float* __restrict__ out, ushort* __restrict__ out_bf,
    const float* __restrict__ qpos, ushort* __restrict__ qadd_bf)
{
    const int r = blockIdx.x;
    const int c = threadIdx.x;
    float v = x[(size_t)r * 256 + c] + y[(size_t)r * 256 + c];
    float s1 = v, s2 = v * v;
#pragma unroll
    for (int msk = 32; msk; msk >>= 1) {
        s1 += __shfl_xor(s1, msk);
        s2 += __shfl_xor(s2, msk);
    }
    __shared__ float red[8];
    int w = c >> 6;
    if ((c & 63) == 0) { red[w] = s1; red[4 + w] = s2; }
    __syncthreads();
    s1 = red[0] + red[1] + red[2] + red[3];
    s2 = red[4] + red[5] + red[6] + red[7];
    float mean = s1 * (1.f / 256.f);
    float var  = s2 * (1.f / 256.f) - mean * mean;
    float inv  = 1.f / sqrtf(var + 1e-5f);
    float o = (v - mean) * inv * g[c] + beta[c];
    out[(size_t)r * 256 + c] = o;
    if (out_bf) out_bf[(size_t)r * 256 + c] = f2b(o);
    if (qadd_bf) qadd_bf[(size_t)r * 256 + c] = f2b(o + qpos[(size_t)r * 256 + c]);
}

// ---------------------------------------------------------------------------
extern "C" void kernel_launch(void* const* d_in, const int* in_sizes, int n_in,
                              void* d_out, int out_size, void* d_ws, size_t ws_size,
                              hipStream_t stream)
{
    const float* tgt      = (const float*)d_in[0];
    const float* qpos     = (const float*)d_in[1];
    const float* refpts   = (const float*)d_in[2];
    const float* src      = (const float*)d_in[3];
    const unsigned char* padmask = (const unsigned char*)d_in[6];
    const float* sa_in_w  = (const float*)d_in[7];
    const float* sa_in_b  = (const float*)d_in[8];
    const float* sa_out_w = (const float*)d_in[9];
    const float* sa_out_b = (const float*)d_in[10];
    const float* ca_off_w = (const float*)d_in[11];
    const float* ca_off_b = (const float*)d_in[12];
    const float* ca_aw_w  = (const float*)d_in[13];
    const float* ca_aw_b  = (const float*)d_in[14];
    const float* ca_val_w = (const float*)d_in[15];
    const float* ca_val_b = (const float*)d_in[16];
    const float* ca_out_w = (const float*)d_in[17];
    const float* ca_out_b = (const float*)d_in[18];
    const float* n1_g     = (const float*)d_in[19];
    const float* n1_b     = (const float*)d_in[20];
    const float* n2_g     = (const float*)d_in[21];
    const float* n2_b     = (const float*)d_in[22];
    const float* n3_g     = (const float*)d_in[23];
    const float* n3_b     = (const float*)d_in[24];
    const float* f1_w     = (const float*)d_in[25];
    const float* f1_b     = (const float*)d_in[26];
    const float* f2_w     = (const float*)d_in[27];
    const float* f2_b     = (const float*)d_in[28];
    float* out = (float*)d_out;
    (void)in_sizes; (void)n_in; (void)out_size; (void)ws_size;

    float* ws = (float*)d_ws;
    size_t fo = 0;
    auto fa = [&](size_t n) { float* p = ws + fo; fo += n; return p; };
    float* buf_p   = fa((size_t)NQ * 256);
    float* t1      = fa((size_t)NQ * 256);
    float* t2      = fa((size_t)NQ * 256);
    float* offaw   = fa((size_t)NQ * 384);
    float* biascat = fa(384);
    fo = (fo + 3) & ~(size_t)3;            // 16B align for ushort region
    ushort* ub = (ushort*)(ws + fo);
    size_t uo = 0;
    auto ua = [&](size_t n) { ushort* p = ub + uo; uo += n; return p; };
    ushort* w_bf    = ua(1015808);
    ushort* q_bf    = ua((size_t)NQ * 256);
    ushort* tgt_bf  = ua((size_t)NQ * 256);
    ushort* q2_bf   = ua((size_t)NQ * 256);
    ushort* qkv_bf  = ua((size_t)NQ * 768);
    ushort* attn_bf = ua((size_t)NQ * 256);
    ushort* dfo_bf  = ua((size_t)NQ * 256);
    ushort* t2_bf   = ua((size_t)NQ * 256);
    ushort* hid_bf  = ua((size_t)NQ * 1024);
    ushort* val_t   = ua((size_t)NV * 256);

    const ushort* w_sa_in  = w_bf + 0;
    const ushort* w_sa_out = w_bf + 196608;
    const ushort* w_offaw  = w_bf + 262144;   // off (256x256) + aw (128x256) contiguous
    const ushort* w_ca_val = w_bf + 360448;
    const ushort* w_ca_out = w_bf + 425984;
    const ushort* w_f1     = w_bf + 491520;
    const ushort* w_f2     = w_bf + 753664;

    dim3 blk(256);
    const int n4 = NQ * 256 / 4;

    WPtrs wp;
    wp.p[0] = sa_in_w; wp.p[1] = sa_out_w; wp.p[2] = ca_off_w; wp.p[3] = ca_aw_w;
    wp.p[4] = ca_val_w; wp.p[5] = ca_out_w; wp.p[6] = f1_w; wp.p[7] = f2_w;
    cvt_w_kernel<<<993, blk, 0, stream>>>(wp, w_bf, ca_off_b, ca_aw_b, biascat);

    // ---- self-attention ----
    cvt_pair_kernel<<<1800, blk, 0, stream>>>(tgt, qpos, q_bf, tgt_bf, n4);
    gemm_mfma<64, false, 1, false, false><<<dim3(4, 113), blk, 0, stream>>>(
        q_bf, w_sa_in, sa_in_b, qkv_bf, NQ, 256, 768, nullptr);
    gemm_mfma<64, false, 1, false, false><<<dim3(2, 113), blk, 0, stream>>>(
        tgt_bf, w_sa_in + 512 * 256, sa_in_b + 512, qkv_bf + 512, NQ, 256, 768, nullptr);
    attn_mfma<<<dim3(15, 8, 8), blk, 0, stream>>>(qkv_bf, attn_bf);
    gemm_mfma<64, false, 0, false, false><<<dim3(2, 113), blk, 0, stream>>>(
        attn_bf, w_sa_out, sa_out_b, buf_p, NQ, 256, 256, nullptr);
    ln_kernel<<<NQ, blk, 0, stream>>>(tgt, buf_p, n2_g, n2_b, t1, nullptr, qpos, q2_bf);

    // ---- deformable cross-attention ----
    gemm_mfma<128, true, 2, false, true><<<dim3(2, 1360), blk, 0, stream>>>(
        src, w_ca_val, ca_val_b, val_t, NV, 256, 256, padmask);
    gemm_mfma<64, false, 0, false, false><<<dim3(3, 113), blk, 0, stream>>>(
        q2_bf, w_offaw, biascat, offaw, NQ, 256, 384, nullptr);
    deform2_kernel<<<3600, blk, 0, stream>>>(val_t, offaw, refpts, dfo_bf);
    gemm_mfma<64, false, 0, false, false><<<dim3(2, 113), blk, 0, stream>>>(
        dfo_bf, w_ca_out, ca_out_b, buf_p, NQ, 256, 256, nullptr);
    ln_kernel<<<NQ, blk, 0, stream>>>(t1, buf_p, n1_g, n1_b, t2, t2_bf, nullptr, nullptr);

    // ---- FFN ----
    gemm_mfma<128, false, 1, true, false><<<dim3(8, 57), blk, 0, stream>>>(
        t2_bf, w_f1, f1_b, hid_bf, NQ, 256, 1024, nullptr);
    gemm_mfma<64, false, 0, false, false><<<dim3(2, 113), blk, 0, stream>>>(
        hid_bf, w_f2, f2_b, buf_p, NQ, 1024, 256, nullptr);
    ln_kernel<<<NQ, blk, 0, stream>>>(t2, buf_p, n3_g, n3_b, out, nullptr, nullptr, nullptr);
}

// Round 5
// 574.391 us; speedup vs baseline: 2.1082x; 1.0142x over previous
//
#include <hip/hip_runtime.h>
#include <cstdint>

constexpr int NB   = 8;
constexpr int LQn  = 900;
constexpr int CD   = 256;
constexpr int LENS = 21760;
constexpr int NQ   = NB * LQn;    // 7200
constexpr int NV   = NB * LENS;   // 174080

using short8 = __attribute__((ext_vector_type(8))) short;
using f32x4  = __attribute__((ext_vector_type(4))) float;

__device__ __forceinline__ ushort f2b(float x) {
    uint32_t u = __builtin_bit_cast(uint32_t, x);
    u += 0x7fffu + ((u >> 16) & 1u);
    return (ushort)(u >> 16);
}
__device__ __forceinline__ float b2f(ushort x) {
    uint32_t u = ((uint32_t)x) << 16;
    return __builtin_bit_cast(float, u);
}
__device__ __forceinline__ float b2f_lo(uint32_t u) {
    return __builtin_bit_cast(float, u << 16);
}
__device__ __forceinline__ float b2f_hi(uint32_t u) {
    return __builtin_bit_cast(float, u & 0xffff0000u);
}
// hardware packed f32x2 -> bf16x2 (RNE), gfx950
__device__ __forceinline__ uint32_t cvtpk(float lo, float hi) {
    uint32_t r;
    asm("v_cvt_pk_bf16_f32 %0, %1, %2" : "=v"(r) : "v"(lo), "v"(hi));
    return r;
}

// ---------------------------------------------------------------------------
// Weight conversion + bias concat for the fused off/aw projection.
// ---------------------------------------------------------------------------
struct WPtrs { const float* p[8]; };
__constant__ const int kWOff[9] = {0, 196608, 262144, 327680, 360448, 425984,
                                   491520, 753664, 1015808};

__global__ __launch_bounds__(256) void cvt_w_kernel(
    WPtrs w, ushort* __restrict__ out,
    const float* __restrict__ offb, const float* __restrict__ awb,
    float* __restrict__ biascat)
{
    if (blockIdx.x == 992) {
        for (int t = threadIdx.x; t < 384; t += 256)
            biascat[t] = t < 256 ? offb[t] : awb[t - 256];
        return;
    }
    int i = blockIdx.x * blockDim.x + threadIdx.x;
    int e = i * 4;
    int s = 0;
#pragma unroll
    for (int k = 1; k < 8; ++k) if (e >= kWOff[k]) s = k;
    float4 v = *reinterpret_cast<const float4*>(w.p[s] + (e - kWOff[s]));
    ushort4 o;
    o.x = f2b(v.x); o.y = f2b(v.y); o.z = f2b(v.z); o.w = f2b(v.w);
    *reinterpret_cast<ushort4*>(out + e) = o;
}

__global__ __launch_bounds__(256) void cvt_pair_kernel(
    const float* __restrict__ a, const float* __restrict__ b,
    ushort* __restrict__ sum_bf, ushort* __restrict__ a_bf, int n4) {
    int i = blockIdx.x * blockDim.x + threadIdx.x;
    if (i >= n4) return;
    float4 va = reinterpret_cast<const float4*>(a)[i];
    float4 vb = reinterpret_cast<const float4*>(b)[i];
    ushort4 s, t;
    s.x = f2b(va.x + vb.x); s.y = f2b(va.y + vb.y);
    s.z = f2b(va.z + vb.z); s.w = f2b(va.w + vb.w);
    reinterpret_cast<ushort4*>(sum_bf)[i] = s;
    t.x = f2b(va.x); t.y = f2b(va.y); t.z = f2b(va.z); t.w = f2b(va.w);
    reinterpret_cast<ushort4*>(a_bf)[i] = t;
}

// ---------------------------------------------------------------------------
// MFMA GEMM, 2-phase double-buffered: C[M x N] = A[M x K] * B[N x K]^T + bias.
// BM x 128 tile, BK=32, 4 waves (2x2). OUTK: 0=f32, 1=bf16, 2=bf16 val-transposed.
// Per K-step: issue next-tile loads -> ds_read+MFMA current -> (cvt+ds_write) ->
// one barrier (drains vmcnt). Loads overlap MFMA.
// ---------------------------------------------------------------------------
template<int BM, bool A_F32, int OUTK, bool RELU, bool MASK>
__global__ __launch_bounds__(256) void gemm_mfma(
    const void* __restrict__ Av, const ushort* __restrict__ B,
    const float* __restrict__ bias, void* __restrict__ Cv,
    int M, int K, int ldc, const unsigned char* __restrict__ rowmask)
{
    constexpr int RIT = BM / 64;   // A staging iterations
    constexpr int FR  = BM / 32;   // M frags per wave
    __shared__ ushort As[2][BM * 32];
    __shared__ ushort Bs[2][4096];

    const int tid = threadIdx.x, lane = tid & 63, wave = tid >> 6;
    const int wr = wave >> 1, wc = wave & 1;
    const int bn = blockIdx.x * 128;
    const int bm = blockIdx.y * BM;
    const int lc15 = lane & 15, lk = lane >> 4;

    const ushort* Abf = (const ushort*)Av;
    const float*  Afp = (const float*)Av;

    f32x4 acc[FR][4] = {};

    int a_off[FR], b_off[4];
#pragma unroll
    for (int fr = 0; fr < FR; ++fr) {
        int r = wr * (BM / 2) + fr * 16 + lc15;
        a_off[fr] = r * 32 + ((lk ^ ((r >> 1) & 3)) * 8);
    }
#pragma unroll
    for (int fc = 0; fc < 4; ++fc) {
        int rb = wc * 64 + fc * 16 + lc15;
        b_off[fc] = rb * 32 + ((lk ^ ((rb >> 1) & 3)) * 8);
    }

    float4 pa0[RIT], pa1[RIT];   // A_F32 in-flight registers

    auto loadA_regs = [&](int k0) {
#pragma unroll
        for (int t = 0; t < RIT; ++t) {
            int s = tid + t * 256;
            int row = s >> 2, p = s & 3;
            int g = p ^ ((row >> 1) & 3);
            size_t ar = (size_t)bm + row; if (ar >= (size_t)M) ar = M - 1;
            const float* gp = Afp + ar * (size_t)K + k0 + g * 8;
            pa0[t] = *reinterpret_cast<const float4*>(gp);
            pa1[t] = *reinterpret_cast<const float4*>(gp + 4);
        }
    };
    auto writeA_lds = [&](int buf) {
#pragma unroll
        for (int t = 0; t < RIT; ++t) {
            int s = tid + t * 256;
            int row = s >> 2, p = s & 3;
            uint4 pk;
            pk.x = cvtpk(pa0[t].x, pa0[t].y);
            pk.y = cvtpk(pa0[t].z, pa0[t].w);
            pk.z = cvtpk(pa1[t].x, pa1[t].y);
            pk.w = cvtpk(pa1[t].z, pa1[t].w);
            *reinterpret_cast<uint4*>(&As[buf][row * 32 + p * 8]) = pk;
        }
    };
    auto stageA_lds = [&](int buf, int k0) {
#pragma unroll
        for (int t = 0; t < RIT; ++t) {
            int row = wave * (16 * RIT) + t * 16 + (lane >> 2);
            int p = lane & 3;
            int g = p ^ ((row >> 1) & 3);
            size_t ar = (size_t)bm + row; if (ar >= (size_t)M) ar = M - 1;
            const ushort* gp = Abf + ar * (size_t)K + k0 + g * 8;
            __builtin_amdgcn_global_load_lds(
                (const __attribute__((address_space(1))) uint32_t*)gp,
                (__attribute__((address_space(3))) uint32_t*)(&As[buf][(wave * RIT + t) * 512]),
                16, 0, 0);
        }
    };
    auto stageB = [&](int buf, int k0) {
#pragma unroll
        for (int t = 0; t < 2; ++t) {
            int row = wave * 32 + t * 16 + (lane >> 2);
            int p = lane & 3;
            int g = p ^ ((row >> 1) & 3);
            const ushort* gp = B + (size_t)(bn + row) * K + k0 + g * 8;
            __builtin_amdgcn_global_load_lds(
                (const __attribute__((address_space(1))) uint32_t*)gp,
                (__attribute__((address_space(3))) uint32_t*)(&Bs[buf][(wave * 2 + t) * 512]),
                16, 0, 0);
        }
    };

    // ---- prologue: fill buffer 0 ----
    if constexpr (A_F32) { loadA_regs(0); writeA_lds(0); }
    else stageA_lds(0, 0);
    stageB(0, 0);
    __syncthreads();

    const int nt = K >> 5;
    int cur = 0;
    for (int t = 0; t < nt; ++t) {
        const int k0n = (t + 1) << 5;
        const bool more = (t + 1 < nt);
        if constexpr (A_F32) {
            if (more) loadA_regs(k0n);         // issue f32 loads (regs)
        } else {
            if (more) stageA_lds(cur ^ 1, k0n); // async into other buffer
        }
        if (more) stageB(cur ^ 1, k0n);

        short8 af[FR], bfr[4];
#pragma unroll
        for (int fr = 0; fr < FR; ++fr) af[fr]  = *reinterpret_cast<const short8*>(&As[cur][a_off[fr]]);
#pragma unroll
        for (int fc = 0; fc < 4; ++fc) bfr[fc] = *reinterpret_cast<const short8*>(&Bs[cur][b_off[fc]]);
#pragma unroll
        for (int fr = 0; fr < FR; ++fr)
#pragma unroll
            for (int fc = 0; fc < 4; ++fc)
                acc[fr][fc] = __builtin_amdgcn_mfma_f32_16x16x32_bf16(
                    af[fr], bfr[fc], acc[fr][fc], 0, 0, 0);

        if constexpr (A_F32) {
            if (more) writeA_lds(cur ^ 1);     // vmcnt wait + cvt + ds_write after MFMA
        }
        __syncthreads();
        cur ^= 1;
    }

    // ---- epilogue ----
#pragma unroll
    for (int fc = 0; fc < 4; ++fc) {
        int col = bn + wc * 64 + fc * 16 + lc15;
        float bv = bias[col];
#pragma unroll
        for (int fr = 0; fr < FR; ++fr) {
            int rb = bm + wr * (BM / 2) + fr * 16 + lk * 4;
#pragma unroll
            for (int r = 0; r < 4; ++r) {
                int row = rb + r;
                if (row < M) {
                    float v = acc[fr][fc][r] + bv;
                    if constexpr (RELU) v = fmaxf(v, 0.f);
                    if constexpr (MASK) { if (rowmask[row]) v = 0.f; }
                    if constexpr (OUTK == 0)
                        ((float*)Cv)[(size_t)row * ldc + col] = v;
                    else if constexpr (OUTK == 1)
                        ((ushort*)Cv)[(size_t)row * ldc + col] = f2b(v);
                    else {
                        int brow = row / LENS;
                        int len  = row - brow * LENS;
                        int hh = col >> 5, ch = col & 31;
                        ((ushort*)Cv)[((size_t)(brow * 8 + hh) * LENS + len) * 32 + ch] = f2b(v);
                    }
                }
            }
        }
    }
}

// ---------------------------------------------------------------------------
// MFMA flash self-attention, pipelined: V double-buffered in LDS, K prefetched
// in registers; one barrier per K/V tile. Block = (64-q tile, h, b), 4 waves.
// ---------------------------------------------------------------------------
__global__ __launch_bounds__(256) void attn_mfma(
    const ushort* __restrict__ qkv, ushort* __restrict__ out)
{
    __shared__ ushort Vt[2][32][72];     // [buf][dh][key]
    __shared__ ushort Plds[4][16][72];   // per-wave P [q][key]

    const int tid = threadIdx.x, lane = tid & 63, wave = tid >> 6;
    const int lq = lane & 15, lg = lane >> 4;
    const int q0 = blockIdx.x * 64;
    const int h = blockIdx.y, b = blockIdx.z;
    const size_t bbase = (size_t)b * LQn * 768;

    int qrow = q0 + wave * 16 + lq; if (qrow > LQn - 1) qrow = LQn - 1;
    short8 aq = *reinterpret_cast<const short8*>(
        qkv + bbase + (size_t)qrow * 768 + h * 32 + lg * 8);

    const int vkey = tid >> 2, vdhc = (tid & 3) * 8;

    auto loadV = [&](int kb) {
        int kg = kb + vkey; if (kg > LQn - 1) kg = LQn - 1;
        return *reinterpret_cast<const short8*>(
            qkv + bbase + (size_t)kg * 768 + 512 + h * 32 + vdhc);
    };
    auto loadK = [&](int kb, short8* bk) {
#pragma unroll
        for (int fc = 0; fc < 4; ++fc) {
            int krow = kb + fc * 16 + lq;
            int kc = krow > LQn - 1 ? LQn - 1 : krow;
            bk[fc] = *reinterpret_cast<const short8*>(
                qkv + bbase + (size_t)kc * 768 + 256 + h * 32 + lg * 8);
        }
    };

    f32x4 accO[2] = {};
    float m[4], l[4];
#pragma unroll
    for (int r = 0; r < 4; ++r) { m[r] = -3.0e38f; l[r] = 0.f; }

    short8 vreg = loadV(0);
    short8 kreg[4]; loadK(0, kreg);

    int cur = 0;
    for (int kt = 0; kt < 15; ++kt) {
        const int kb = kt * 64;
        // stage V(kt) into LDS buffer cur
#pragma unroll
        for (int j = 0; j < 8; ++j) Vt[cur][vdhc + j][vkey] = (ushort)vreg[j];
        __syncthreads();

        // QK^T on prefetched K
        f32x4 s4[4];
#pragma unroll
        for (int fc = 0; fc < 4; ++fc) {
            f32x4 z = {};
            s4[fc] = __builtin_amdgcn_mfma_f32_16x16x32_bf16(aq, kreg[fc], z, 0, 0, 0);
        }
        // prefetch next tile's V/K (overlaps softmax + PV)
        if (kt + 1 < 15) { vreg = loadV(kb + 64); loadK(kb + 64, kreg); }

#pragma unroll
        for (int fc = 0; fc < 4; ++fc) {
            int krow = kb + fc * 16 + lq;
            bool inval = krow >= LQn;
#pragma unroll
            for (int r = 0; r < 4; ++r)
                s4[fc][r] = inval ? -3.0e38f : s4[fc][r] * 0.17677669529663687f;
        }

#pragma unroll
        for (int r = 0; r < 4; ++r) {
            float rm = fmaxf(fmaxf(s4[0][r], s4[1][r]), fmaxf(s4[2][r], s4[3][r]));
            rm = fmaxf(rm, __shfl_xor(rm, 1));
            rm = fmaxf(rm, __shfl_xor(rm, 2));
            rm = fmaxf(rm, __shfl_xor(rm, 4));
            rm = fmaxf(rm, __shfl_xor(rm, 8));
            float mn = fmaxf(m[r], rm);
            float esc = __expf(m[r] - mn);
            float rs = 0.f;
#pragma unroll
            for (int fc = 0; fc < 4; ++fc) {
                float p = __expf(s4[fc][r] - mn);
                s4[fc][r] = p; rs += p;
            }
            rs += __shfl_xor(rs, 1); rs += __shfl_xor(rs, 2);
            rs += __shfl_xor(rs, 4); rs += __shfl_xor(rs, 8);
            m[r] = mn;
            l[r] = l[r] * esc + rs;
            accO[0][r] *= esc; accO[1][r] *= esc;
        }

#pragma unroll
        for (int fc = 0; fc < 4; ++fc)
#pragma unroll
            for (int r = 0; r < 4; ++r)
                Plds[wave][lg * 4 + r][fc * 16 + lq] = f2b(s4[fc][r]);

#pragma unroll
        for (int ks = 0; ks < 2; ++ks) {
            short8 ap = *reinterpret_cast<const short8*>(&Plds[wave][lq][ks * 32 + lg * 8]);
#pragma unroll
            for (int fc = 0; fc < 2; ++fc) {
                short8 bv = *reinterpret_cast<const short8*>(&Vt[cur][fc * 16 + lq][ks * 32 + lg * 8]);
                accO[fc] = __builtin_amdgcn_mfma_f32_16x16x32_bf16(ap, bv, accO[fc], 0, 0, 0);
            }
        }
        cur ^= 1;
    }

#pragma unroll
    for (int r = 0; r < 4; ++r) {
        int q = q0 + wave * 16 + lg * 4 + r;
        if (q < LQn) {
            float invl = 1.f / l[r];
#pragma unroll
            for (int fc = 0; fc < 2; ++fc)
                out[((size_t)b * LQn + q) * 256 + h * 32 + fc * 16 + lq] =
                    f2b(accO[fc][r] * invl);
        }
    }
}

// ---------------------------------------------------------------------------
// Deformable sampling v2: value in (b, h, LENS, 32) layout; 16 lanes per
// (bq,h) group, 2 channels/lane; params computed by lane=sample, staged in LDS.
// ---------------------------------------------------------------------------
__global__ __launch_bounds__(256) void deform2_kernel(
    const ushort* __restrict__ valt,   // (NB*8, LENS, 32) bf16
    const float* __restrict__ offaw,   // (NQ, 384): [0:256) off, [256:384) aw
    const float* __restrict__ ref,     // (NB, LQ, NL, 2)
    ushort* __restrict__ out)          // (NQ, 256) bf16
{
    __shared__ int   Pi[16][16][4];
    __shared__ float Pw[16][16][4];

    const int tid = threadIdx.x;
    const int grp = tid >> 4;          // 0..15
    const int lane = tid & 15;
    const int gg = blockIdx.x * 16 + grp;     // 0..57599, h-major
    const int h  = gg / 7200;
    const int bq = gg - h * 7200;
    const int b  = bq / LQn;

    const float* row = offaw + (size_t)bq * 384;
    float aval = row[256 + h * 16 + lane];
    float mx = aval;
    mx = fmaxf(mx, __shfl_xor(mx, 1));
    mx = fmaxf(mx, __shfl_xor(mx, 2));
    mx = fmaxf(mx, __shfl_xor(mx, 4));
    mx = fmaxf(mx, __shfl_xor(mx, 8));
    float e = __expf(aval - mx);
    float se = e;
    se += __shfl_xor(se, 1); se += __shfl_xor(se, 2);
    se += __shfl_xor(se, 4); se += __shfl_xor(se, 8);
    float a = e / se;

    const int lv = lane >> 2;
    const int W = 128 >> lv;
    const int STl[4] = {0, 16384, 20480, 21504};
    const float Wf = (float)W;
    float2 off2 = *reinterpret_cast<const float2*>(row + h * 32 + lane * 2);
    float rx = ref[(size_t)bq * 8 + lv * 2];
    float ry = ref[(size_t)bq * 8 + lv * 2 + 1];
    float x = (rx + off2.x / Wf) * Wf - 0.5f;
    float y = (ry + off2.y / Wf) * Wf - 0.5f;
    float x0f = floorf(x), y0f = floorf(y);
    int x0 = (int)x0f, y0 = (int)y0f;
    float wx = x - x0f, wy = y - y0f;
    float vx0 = (x0 >= 0 && x0 < W) ? 1.f : 0.f;
    float vx1 = (x0 + 1 >= 0 && x0 + 1 < W) ? 1.f : 0.f;
    float vy0 = (y0 >= 0 && y0 < W) ? 1.f : 0.f;
    float vy1 = (y0 + 1 >= 0 && y0 + 1 < W) ? 1.f : 0.f;
    int x0c = min(max(x0, 0), W - 1), x1c = min(max(x0 + 1, 0), W - 1);
    int y0c = min(max(y0, 0), W - 1), y1c = min(max(y0 + 1, 0), W - 1);
    int base = STl[lv];
    Pi[grp][lane][0] = base + y0c * W + x0c;
    Pi[grp][lane][1] = base + y0c * W + x1c;
    Pi[grp][lane][2] = base + y1c * W + x0c;
    Pi[grp][lane][3] = base + y1c * W + x1c;
    Pw[grp][lane][0] = (1.f - wx) * (1.f - wy) * vx0 * vy0 * a;
    Pw[grp][lane][1] = wx * (1.f - wy) * vx1 * vy0 * a;
    Pw[grp][lane][2] = (1.f - wx) * wy * vx0 * vy1 * a;
    Pw[grp][lane][3] = wx * wy * vx1 * vy1 * a;

    const ushort* vb = valt + (size_t)(b * 8 + h) * (LENS * 32);
    float accx = 0.f, accy = 0.f;
#pragma unroll 4
    for (int s = 0; s < 16; ++s) {
        int4  idx = *reinterpret_cast<const int4*>(Pi[grp][s]);
        float4 w  = *reinterpret_cast<const float4*>(Pw[grp][s]);
        uint32_t u00 = *reinterpret_cast<const uint32_t*>(vb + idx.x * 32 + lane * 2);
        uint32_t u10 = *reinterpret_cast<const uint32_t*>(vb + idx.y * 32 + lane * 2);
        uint32_t u01 = *reinterpret_cast<const uint32_t*>(vb + idx.z * 32 + lane * 2);
        uint32_t u11 = *reinterpret_cast<const uint32_t*>(vb + idx.w * 32 + lane * 2);
        accx = fmaf(w.x, b2f_lo(u00), accx); accy = fmaf(w.x, b2f_hi(u00), accy);
        accx = fmaf(w.y, b2f_lo(u10), accx); accy = fmaf(w.y, b2f_hi(u10), accy);
        accx = fmaf(w.z, b2f_lo(u01), accx); accy = fmaf(w.z, b2f_hi(u01), accy);
        accx = fmaf(w.w, b2f_lo(u11), accx); accy = fmaf(w.w, b2f_hi(u11), accy);
    }
    uint32_t pack = ((uint32_t)f2b(accy) << 16) | (uint32_t)f2b(accx);
    *reinterpret_cast<uint32_t*>(out + (size_t)bq * 256 + h * 32 + lane * 2) = pack;
}

// ---------------------------------------------------------------------------
// Fused residual + LayerNorm; optional bf16 copy and bf16(x+qpos) output.
// ---------------------------------------------------------------------------
__global__ __launch_bounds__(256) void ln_kernel(
    const float* __restrict__ x, const float* __restrict__ y,
    const float* __restrict__ g, const float* __restrict__ beta,
    float* __restrict__ out, ushort* __restrict__ out_bf,
    const float* __restrict__ qpos, ushort* __restrict__ qadd_bf)
{
    const int r = blockIdx.x;
    const int c = threadIdx.x;
    float v = x[(size_t)r * 256 + c] + y[(size_t)r * 256 + c];
    float s1 = v, s2 = v * v;
#pragma unroll
    for (int msk = 32; msk; msk >>= 1) {
        s1 += __shfl_xor(s1, msk);
        s2 += __shfl_xor(s2, msk);
    }
    __shared__ float red[8];
    int w = c >> 6;
    if ((c & 63) == 0) { red[w] = s1; red[4 + w] = s2; }
    __syncthreads();
    s1 = red[0] + red[1] + red[2] + red[3];
    s2 = red[4] + red[5] + red[6] + red[7];
    float mean = s1 * (1.f / 256.f);
    float var  = s2 * (1.f / 256.f) - mean * mean;
    float inv  = 1.f / sqrtf(var + 1e-5f);
    float o = (v - mean) * inv * g[c] + beta[c];
    out[(size_t)r * 256 + c] = o;
    if (out_bf) out_bf[(size_t)r * 256 + c] = f2b(o);
    if (qadd_bf) qadd_bf[(size_t)r * 256 + c] = f2b(o + qpos[(size_t)r * 256 + c]);
}

// ---------------------------------------------------------------------------
extern "C" void kernel_launch(void* const* d_in, const int* in_sizes, int n_in,
                              void* d_out, int out_size, void* d_ws, size_t ws_size,
                              hipStream_t stream)
{
    const float* tgt      = (const float*)d_in[0];
    const float* qpos     = (const float*)d_in[1];
    const float* refpts   = (const float*)d_in[2];
    const float* src      = (const float*)d_in[3];
    const unsigned char* padmask = (const unsigned char*)d_in[6];
    const float* sa_in_w  = (const float*)d_in[7];
    const float* sa_in_b  = (const float*)d_in[8];
    const float* sa_out_w = (const float*)d_in[9];
    const float* sa_out_b = (const float*)d_in[10];
    const float* ca_off_w = (const float*)d_in[11];
    const float* ca_off_b = (const float*)d_in[12];
    const float* ca_aw_w  = (const float*)d_in[13];
    const float* ca_aw_b  = (const float*)d_in[14];
    const float* ca_val_w = (const float*)d_in[15];
    const float* ca_val_b = (const float*)d_in[16];
    const float* ca_out_w = (const float*)d_in[17];
    const float* ca_out_b = (const float*)d_in[18];
    const float* n1_g     = (const float*)d_in[19];
    const float* n1_b     = (const float*)d_in[20];
    const float* n2_g     = (const float*)d_in[21];
    const float* n2_b     = (const float*)d_in[22];
    const float* n3_g     = (const float*)d_in[23];
    const float* n3_b     = (const float*)d_in[24];
    const float* f1_w     = (const float*)d_in[25];
    const float* f1_b     = (const float*)d_in[26];
    const float* f2_w     = (const float*)d_in[27];
    const float* f2_b     = (const float*)d_in[28];
    float* out = (float*)d_out;
    (void)in_sizes; (void)n_in; (void)out_size; (void)ws_size;

    float* ws = (float*)d_ws;
    size_t fo = 0;
    auto fa = [&](size_t n) { float* p = ws + fo; fo += n; return p; };
    float* buf_p   = fa((size_t)NQ * 256);
    float* t1      = fa((size_t)NQ * 256);
    float* t2      = fa((size_t)NQ * 256);
    float* offaw   = fa((size_t)NQ * 384);
    float* biascat = fa(384);
    fo = (fo + 3) & ~(size_t)3;            // 16B align for ushort region
    ushort* ub = (ushort*)(ws + fo);
    size_t uo = 0;
    auto ua = [&](size_t n) { ushort* p = ub + uo; uo += n; return p; };
    ushort* w_bf    = ua(1015808);
    ushort* q_bf    = ua((size_t)NQ * 256);
    ushort* tgt_bf  = ua((size_t)NQ * 256);
    ushort* q2_bf   = ua((size_t)NQ * 256);
    ushort* qkv_bf  = ua((size_t)NQ * 768);
    ushort* attn_bf = ua((size_t)NQ * 256);
    ushort* dfo_bf  = ua((size_t)NQ * 256);
    ushort* t2_bf   = ua((size_t)NQ * 256);
    ushort* hid_bf  = ua((size_t)NQ * 1024);
    ushort* val_t   = ua((size_t)NV * 256);

    const ushort* w_sa_in  = w_bf + 0;
    const ushort* w_sa_out = w_bf + 196608;
    const ushort* w_offaw  = w_bf + 262144;   // off (256x256) + aw (128x256) contiguous
    const ushort* w_ca_val = w_bf + 360448;
    const ushort* w_ca_out = w_bf + 425984;
    const ushort* w_f1     = w_bf + 491520;
    const ushort* w_f2     = w_bf + 753664;

    dim3 blk(256);
    const int n4 = NQ * 256 / 4;

    WPtrs wp;
    wp.p[0] = sa_in_w; wp.p[1] = sa_out_w; wp.p[2] = ca_off_w; wp.p[3] = ca_aw_w;
    wp.p[4] = ca_val_w; wp.p[5] = ca_out_w; wp.p[6] = f1_w; wp.p[7] = f2_w;
    cvt_w_kernel<<<993, blk, 0, stream>>>(wp, w_bf, ca_off_b, ca_aw_b, biascat);

    // ---- self-attention ----
    cvt_pair_kernel<<<1800, blk, 0, stream>>>(tgt, qpos, q_bf, tgt_bf, n4);
    gemm_mfma<64, false, 1, false, false><<<dim3(4, 113), blk, 0, stream>>>(
        q_bf, w_sa_in, sa_in_b, qkv_bf, NQ, 256, 768, nullptr);
    gemm_mfma<64, false, 1, false, false><<<dim3(2, 113), blk, 0, stream>>>(
        tgt_bf, w_sa_in + 512 * 256, sa_in_b + 512, qkv_bf + 512, NQ, 256, 768, nullptr);
    attn_mfma<<<dim3(15, 8, 8), blk, 0, stream>>>(qkv_bf, attn_bf);
    gemm_mfma<64, false, 0, false, false><<<dim3(2, 113), blk, 0, stream>>>(
        attn_bf, w_sa_out, sa_out_b, buf_p, NQ, 256, 256, nullptr);
    ln_kernel<<<NQ, blk, 0, stream>>>(tgt, buf_p, n2_g, n2_b, t1, nullptr, qpos, q2_bf);

    // ---- deformable cross-attention ----
    gemm_mfma<128, true, 2, false, true><<<dim3(2, 1360), blk, 0, stream>>>(
        src, w_ca_val, ca_val_b, val_t, NV, 256, 256, padmask);
    gemm_mfma<64, false, 0, false, false><<<dim3(3, 113), blk, 0, stream>>>(
        q2_bf, w_offaw, biascat, offaw, NQ, 256, 384, nullptr);
    deform2_kernel<<<3600, blk, 0, stream>>>(val_t, offaw, refpts, dfo_bf);
    gemm_mfma<64, false, 0, false, false><<<dim3(2, 113), blk, 0, stream>>>(
        dfo_bf, w_ca_out, ca_out_b, buf_p, NQ, 256, 256, nullptr);
    ln_kernel<<<NQ, blk, 0, stream>>>(t1, buf_p, n1_g, n1_b, t2, t2_bf, nullptr, nullptr);

    // ---- FFN ----
    gemm_mfma<128, false, 1, true, false><<<dim3(8, 57), blk, 0, stream>>>(
        t2_bf, w_f1, f1_b, hid_bf, NQ, 256, 1024, nullptr);
    gemm_mfma<64, false, 0, false, false><<<dim3(2, 113), blk, 0, stream>>>(
        hid_bf, w_f2, f2_b, buf_p, NQ, 1024, 256, nullptr);
    ln_kernel<<<NQ, blk, 0, stream>>>(t2, buf_p, n3_g, n3_b, out, nullptr, nullptr, nullptr);
}